// Round 9
// baseline (537.764 us; speedup 1.0000x reference)
//
#include <hip/hip_runtime.h>

typedef _Float16 half8 __attribute__((ext_vector_type(8)));
typedef _Float16 half4 __attribute__((ext_vector_type(4)));
typedef float    f32x4 __attribute__((ext_vector_type(4)));

#define MFMA32(a,b,c) __builtin_amdgcn_mfma_f32_16x16x32_f16(a,b,c,0,0,0)
#define MFMA16(a,b,c) __builtin_amdgcn_mfma_f32_16x16x16f16(a,b,c,0,0,0)

#if __has_builtin(__builtin_amdgcn_exp2f)
#define EXP2F(x) __builtin_amdgcn_exp2f(x)
#else
#define EXP2F(x) exp2f(x)
#endif

// Scheduling fence: nothing crosses. Forces issued loads to stay batched
// (R8 lesson: compiler sinks loads to uses -> zero memory-level parallelism).
#if __has_builtin(__builtin_amdgcn_sched_barrier)
#define SCHED_FENCE() __builtin_amdgcn_sched_barrier(0)
#else
#define SCHED_FENCE() asm volatile("" ::: "memory")
#endif

// Q LDS: 128 rows x 64 halves, 8-half blocks XOR-swizzled by row.
#define LADDR(row, col8) ((((row)) << 6) + ((((col8) ^ ((row) & 7))) << 3))
// Sb: per-wave-private S staging. [wv][G=n-pair][col=m 0..16][k=h+8*(n&1)]
#define SB(wv,G,col,k) ((wv)*3136 + (G)*392 + (col)*24 + (k))
// Wb: mixed weights. [g][n 0..16][m 0..64]; n stride 72, g stride 1160.
#define WB(g,n,m) ((g)*1160 + (n)*72 + (m))

// scale = DH^-0.5 = 1/8, folded together with log2(e) into Q so softmax uses exp2.
static constexpr float SCALE_LOG2E = 0.18033688011112042f;

static constexpr size_t QH_OFF = 0;
static constexpr size_t KH_OFF = (size_t)8  << 20;
static constexpr size_t VT_OFF = (size_t)16 << 20;
static constexpr size_t O_OFF  = (size_t)24 << 20;

// ---------------------------------------------------------------------------
// K1: qkv projection. C[8192,1536] = X[8192,512] @ W[512,1536] + b.
// Scatters to Qh[b][h][n][64] (xSCALE_LOG2E), Kh[b][h][n][64], Vt[b][h][64][n], all f16.
// ---------------------------------------------------------------------------
__global__ __launch_bounds__(256)
void k_qkv(const float* __restrict__ x, const float* __restrict__ w,
           const float* __restrict__ bias, _Float16* __restrict__ Qh,
           _Float16* __restrict__ Kh, _Float16* __restrict__ Vt)
{
  __shared__ __align__(16) _Float16 Xs[64*40];
  __shared__ __align__(16) _Float16 Wt[64*40];
  const int tid = threadIdx.x;
  const int wv = tid >> 6, lane = tid & 63, l15 = lane & 15, qd = lane >> 4;
  const int row0 = blockIdx.x * 64, col0 = blockIdx.y * 64;

  const int xr = tid >> 2, xc = (tid & 3) * 8;
  const int wk = tid >> 3, wc = (tid & 7) * 8;

  f32x4 acc[4] = {{0.f,0.f,0.f,0.f},{0.f,0.f,0.f,0.f},{0.f,0.f,0.f,0.f},{0.f,0.f,0.f,0.f}};

  for (int k0 = 0; k0 < 512; k0 += 32) {
    f32x4 a0 = *(const f32x4*)(x + (size_t)(row0 + xr) * 512 + k0 + xc);
    f32x4 a1 = *(const f32x4*)(x + (size_t)(row0 + xr) * 512 + k0 + xc + 4);
    f32x4 b0 = *(const f32x4*)(w + (size_t)(k0 + wk) * 1536 + col0 + wc);
    f32x4 b1 = *(const f32x4*)(w + (size_t)(k0 + wk) * 1536 + col0 + wc + 4);
    half8 hx;
#pragma unroll
    for (int j = 0; j < 4; j++) { hx[j] = (_Float16)a0[j]; hx[j+4] = (_Float16)a1[j]; }
    *(half8*)&Xs[xr*40 + xc] = hx;
#pragma unroll
    for (int j = 0; j < 4; j++) {
      Wt[(wc+j  )*40 + wk] = (_Float16)b0[j];
      Wt[(wc+j+4)*40 + wk] = (_Float16)b1[j];
    }
    __syncthreads();
    half8 af = *(const half8*)&Xs[(wv*16 + l15)*40 + qd*8];
#pragma unroll
    for (int ct = 0; ct < 4; ct++) {
      half8 bf = *(const half8*)&Wt[(ct*16 + l15)*40 + qd*8];
      acc[ct] = MFMA32(af, bf, acc[ct]);
    }
    __syncthreads();
  }
#pragma unroll
  for (int ct = 0; ct < 4; ct++) {
    const int c = col0 + ct*16 + l15;
    const int sec = c >> 9, hh = (c >> 6) & 7, d = c & 63;
    const float bv = bias[c];
#pragma unroll
    for (int i = 0; i < 4; i++) {
      const int row = row0 + wv*16 + qd*4 + i;
      const int bb = row >> 11, n = row & 2047;
      float v = acc[ct][i] + bv;
      if (sec == 0)
        Qh[((size_t)((bb*8 + hh)*2048 + n))*64 + d] = (_Float16)(v * SCALE_LOG2E);
      else if (sec == 1)
        Kh[((size_t)((bb*8 + hh)*2048 + n))*64 + d] = (_Float16)v;
      else
        Vt[((size_t)((bb*8 + hh)*64 + d))*2048 + n] = (_Float16)v;
    }
  }
}

// ---------------------------------------------------------------------------
// K2: FUSED attention. Grid 512 = 128nt x 4b. Per block: 16 n-rows, one b.
// Sweep 1: QK (K batched + SCHED_FENCE) -> Sb -> mix1 MFMA16 -> exp2 -> l.
// Sweep 2: (b) mix1(seed)->exp2->mix2->Wb ; bar ;
//          (c) [V batch + FENCE + PV] then [K batch + FENCE + QK'] ; bar.
// SCHED_FENCE after each load cluster forces all 16 loads in flight.
// ---------------------------------------------------------------------------
__global__ __launch_bounds__(256, 2)
void k_attn(const _Float16* __restrict__ Qh, const _Float16* __restrict__ Kh,
            const _Float16* __restrict__ Vt, const float* __restrict__ th1,
            const float* __restrict__ th2, _Float16* __restrict__ Obuf)
{
  __shared__ __align__(16) _Float16 Qs[8192];    // 16384 B
  __shared__ __align__(16) _Float16 Sb[12544];   // 25088 B
  __shared__ __align__(16) _Float16 Wb[9280];    // 18560 B
  __shared__ float Lw[4][16][8];                 // 2048 B
  __shared__ float nlgL[128];                    // 512 B  (total 62592 B)
  const int tid = threadIdx.x;
  const int wv = tid >> 6, lane = tid & 63, l15 = lane & 15, qd = lane >> 4;
  const int b = blockIdx.x & 3, nt = blockIdx.x >> 2;
  const int n0 = nt << 4;

  half4 a1f, b2f;
#pragma unroll
  for (int j = 0; j < 4; j++) {
    const bool diag = ((l15 >> 3) == (qd >> 1));
    a1f[j] = diag ? (_Float16)th1[(l15 & 7)*8 + (qd & 1)*4 + j] : (_Float16)0.f;
    b2f[j] = diag ? (_Float16)th2[(l15 & 7)*8 + (qd & 1)*4 + j] : (_Float16)0.f;
  }

  // stage Q block: 8h x 16n x 64d
#pragma unroll
  for (int jj = 0; jj < 4; jj++) {
    const int c = tid + 256*jj;
    const int row = c >> 3, dc = c & 7;
    const int h = row >> 4, n = row & 15;
    *(half8*)&Qs[LADDR(row, dc)] =
      *(const half8*)(Qh + ((size_t)((b*8+h)*2048 + n0 + n))*64 + dc*8);
  }
  __syncthreads();

  const _Float16* kbase = Kh + (size_t)(b*8)*2048*64;
  const _Float16* vbase = Vt + (size_t)(b*8)*64*2048;

  // ---------------- Sweep 1: denominators ----------------
  float lacc[8][4];
#pragma unroll
  for (int G = 0; G < 8; G++)
#pragma unroll
    for (int i = 0; i < 4; i++) lacc[G][i] = 0.f;

  for (int it = 0; it < 32; it++) {
    const int mmw = it*64 + wv*16;
    half8 ka[8][2];
#pragma unroll
    for (int h = 0; h < 8; h++) {
      const _Float16* kp = kbase + ((size_t)(h*2048 + mmw + l15))*64 + qd*8;
      ka[h][0] = *(const half8*)kp;
      ka[h][1] = *(const half8*)(kp + 32);
    }
    SCHED_FENCE();   // all 16 K loads issued before any consumer
    half8 hh[4];
#pragma unroll
    for (int h = 0; h < 8; h++) {
      half8 qb0 = *(const half8*)&Qs[LADDR(h*16 + l15, qd)];
      half8 qb1 = *(const half8*)&Qs[LADDR(h*16 + l15, 4 + qd)];
      f32x4 a = {0.f,0.f,0.f,0.f};
      a = MFMA32(ka[h][0], qb0, a);
      a = MFMA32(ka[h][1], qb1, a);
#pragma unroll
      for (int i = 0; i < 4; i++) hh[i][h] = (_Float16)a[i];
    }
#pragma unroll
    for (int i = 0; i < 4; i++)
      *(half8*)&Sb[SB(wv, l15 >> 1, qd*4 + i, (l15 & 1)*8)] = hh[i];
#pragma unroll
    for (int G = 0; G < 8; G++) {
      half4 b1 = *(const half4*)&Sb[SB(wv, G, l15, qd*4)];
      f32x4 c1 = MFMA16(a1f, b1, ((f32x4){0.f,0.f,0.f,0.f}));
#pragma unroll
      for (int i = 0; i < 4; i++) lacc[G][i] += EXP2F(c1[i]);
    }
  }

#pragma unroll
  for (int G = 0; G < 8; G++)
#pragma unroll
    for (int i = 0; i < 4; i++) {
      float v = lacc[G][i];
      v += __shfl_xor(v, 1); v += __shfl_xor(v, 2);
      v += __shfl_xor(v, 4); v += __shfl_xor(v, 8);
      lacc[G][i] = v;
    }
  if (l15 == 0) {
#pragma unroll
    for (int G = 0; G < 8; G++)
#pragma unroll
      for (int i = 0; i < 4; i++)
        Lw[wv][G*2 + (qd >> 1)][(qd & 1)*4 + i] = lacc[G][i];
  }
  __syncthreads();
  if (tid < 128) {
    const int n = tid >> 3, g = tid & 7;
    nlgL[n*8 + g] = -__log2f(Lw[0][n][g] + Lw[1][n][g] + Lw[2][n][g] + Lw[3][n][g]);
  }

  // ---------------- Sweep 2: PV ----------------
  f32x4 og[2][4];
#pragma unroll
  for (int u = 0; u < 2; u++)
#pragma unroll
    for (int dt = 0; dt < 4; dt++)
      og[u][dt] = (f32x4){0.f,0.f,0.f,0.f};

  // (a) prologue for it=0
  {
    const int mmw = wv*16;
    half8 ka[8][2];
#pragma unroll
    for (int h = 0; h < 8; h++) {
      const _Float16* kp = kbase + ((size_t)(h*2048 + mmw + l15))*64 + qd*8;
      ka[h][0] = *(const half8*)kp;
      ka[h][1] = *(const half8*)(kp + 32);
    }
    SCHED_FENCE();
    half8 hh[4];
#pragma unroll
    for (int h = 0; h < 8; h++) {
      half8 qb0 = *(const half8*)&Qs[LADDR(h*16 + l15, qd)];
      half8 qb1 = *(const half8*)&Qs[LADDR(h*16 + l15, 4 + qd)];
      f32x4 a = {0.f,0.f,0.f,0.f};
      a = MFMA32(ka[h][0], qb0, a);
      a = MFMA32(ka[h][1], qb1, a);
#pragma unroll
      for (int i = 0; i < 4; i++) hh[i][h] = (_Float16)a[i];
    }
#pragma unroll
    for (int i = 0; i < 4; i++)
      *(half8*)&Sb[SB(wv, l15 >> 1, qd*4 + i, (l15 & 1)*8)] = hh[i];
  }
  __syncthreads();   // covers nlgL + prologue

  for (int it = 0; it < 32; it++) {
    const int mm = it*64;

    // (b) mix1 (seeded) -> exp2 -> mix2 -> Wb
#pragma unroll
    for (int G = 0; G < 8; G++) {
      half4 b1 = *(const half4*)&Sb[SB(wv, G, l15, qd*4)];
      f32x4 cs = *(const f32x4*)&nlgL[(G*2 + (qd >> 1))*8 + (qd & 1)*4];
      f32x4 c1 = MFMA16(a1f, b1, cs);
      half4 a2;
#pragma unroll
      for (int i = 0; i < 4; i++) a2[i] = (_Float16)EXP2F(c1[i]);
      f32x4 c2 = MFMA16(a2, b2f, ((f32x4){0.f,0.f,0.f,0.f}));
      half4 w4;
#pragma unroll
      for (int i = 0; i < 4; i++) w4[i] = (_Float16)c2[i];
      *(half4*)&Wb[WB(l15 & 7, G*2 + (l15 >> 3), wv*16 + qd*4)] = w4;
    }
    __syncthreads();

    // (c1) PV with batched V loads forced in flight
    half8 wf[2][2];
#pragma unroll
    for (int u = 0; u < 2; u++)
#pragma unroll
      for (int mc = 0; mc < 2; mc++)
        wf[u][mc] = *(const half8*)&Wb[WB(wv*2 + u, l15, mc*32 + qd*8)];
    half8 vb[2][2][4];
#pragma unroll
    for (int u = 0; u < 2; u++)
#pragma unroll
      for (int mc = 0; mc < 2; mc++)
#pragma unroll
        for (int dt = 0; dt < 4; dt++)
          vb[u][mc][dt] = *(const half8*)(vbase +
              (size_t)((wv*2+u)*64 + dt*16 + l15)*2048 + mm + mc*32 + qd*8);
    SCHED_FENCE();   // all 16 V loads issued before any PV MFMA
#pragma unroll
    for (int u = 0; u < 2; u++)
#pragma unroll
      for (int mc = 0; mc < 2; mc++)
#pragma unroll
        for (int dt = 0; dt < 4; dt++)
          og[u][dt] = MFMA32(wf[u][mc], vb[u][mc][dt], og[u][dt]);

    // (c2) QK for it+1, batched K loads forced in flight
    if (it < 31) {
      const int mmw = mm + 64 + wv*16;
      half8 ka[8][2];
#pragma unroll
      for (int h = 0; h < 8; h++) {
        const _Float16* kp = kbase + ((size_t)(h*2048 + mmw + l15))*64 + qd*8;
        ka[h][0] = *(const half8*)kp;
        ka[h][1] = *(const half8*)(kp + 32);
      }
      SCHED_FENCE();
      half8 hh[4];
#pragma unroll
      for (int h = 0; h < 8; h++) {
        half8 qb0 = *(const half8*)&Qs[LADDR(h*16 + l15, qd)];
        half8 qb1 = *(const half8*)&Qs[LADDR(h*16 + l15, 4 + qd)];
        f32x4 a = {0.f,0.f,0.f,0.f};
        a = MFMA32(ka[h][0], qb0, a);
        a = MFMA32(ka[h][1], qb1, a);
#pragma unroll
        for (int i = 0; i < 4; i++) hh[i][h] = (_Float16)a[i];
      }
#pragma unroll
      for (int i = 0; i < 4; i++)
        *(half8*)&Sb[SB(wv, l15 >> 1, qd*4 + i, (l15 & 1)*8)] = hh[i];
    }
    __syncthreads();
  }

  // epilogue
  _Float16* Op = Obuf + ((size_t)(b*2048 + n0))*512;
#pragma unroll
  for (int u = 0; u < 2; u++)
#pragma unroll
    for (int dt = 0; dt < 4; dt++)
#pragma unroll
      for (int i = 0; i < 4; i++)
        Op[(size_t)(qd*4 + i)*512 + (wv*2+u)*64 + dt*16 + l15] = (_Float16)og[u][dt][i];
}

// ---------------------------------------------------------------------------
// K3: output projection. out[8192,512] = Obuf @ w_out[512,512] + b_out (fp32)
// ---------------------------------------------------------------------------
__global__ __launch_bounds__(256)
void k_oproj(const _Float16* __restrict__ Ob, const float* __restrict__ w,
             const float* __restrict__ bias, float* __restrict__ out)
{
  __shared__ __align__(16) _Float16 Xs[64*40];
  __shared__ __align__(16) _Float16 Wt[64*40];
  const int tid = threadIdx.x;
  const int wv = tid >> 6, lane = tid & 63, l15 = lane & 15, qd = lane >> 4;
  const int row0 = blockIdx.x * 64, col0 = blockIdx.y * 64;
  const int xr = tid >> 2, xc = (tid & 3) * 8;
  const int wk = tid >> 3, wc = (tid & 7) * 8;

  f32x4 acc[4] = {{0.f,0.f,0.f,0.f},{0.f,0.f,0.f,0.f},{0.f,0.f,0.f,0.f},{0.f,0.f,0.f,0.f}};

  for (int k0 = 0; k0 < 512; k0 += 32) {
    *(half8*)&Xs[xr*40 + xc] = *(const half8*)(Ob + (size_t)(row0 + xr)*512 + k0 + xc);
    f32x4 b0 = *(const f32x4*)(w + (size_t)(k0 + wk)*512 + col0 + wc);
    f32x4 b1 = *(const f32x4*)(w + (size_t)(k0 + wk)*512 + col0 + wc + 4);
#pragma unroll
    for (int j = 0; j < 4; j++) {
      Wt[(wc+j  )*40 + wk] = (_Float16)b0[j];
      Wt[(wc+j+4)*40 + wk] = (_Float16)b1[j];
    }
    __syncthreads();
    half8 af = *(const half8*)&Xs[(wv*16 + l15)*40 + qd*8];
#pragma unroll
    for (int ct = 0; ct < 4; ct++) {
      half8 bf = *(const half8*)&Wt[(ct*16 + l15)*40 + qd*8];
      acc[ct] = MFMA32(af, bf, acc[ct]);
    }
    __syncthreads();
  }
#pragma unroll
  for (int ct = 0; ct < 4; ct++) {
    const int c = col0 + ct*16 + l15;
    const float bv = bias[c];
#pragma unroll
    for (int i = 0; i < 4; i++) {
      const int row = row0 + wv*16 + qd*4 + i;
      out[(size_t)row*512 + c] = acc[ct][i] + bv;
    }
  }
}

// ---------------------------------------------------------------------------
extern "C" void kernel_launch(void* const* d_in, const int* in_sizes, int n_in,
                              void* d_out, int out_size, void* d_ws, size_t ws_size,
                              hipStream_t stream)
{
  (void)in_sizes; (void)n_in; (void)out_size;
  const float* x     = (const float*)d_in[0];
  const float* w_qkv = (const float*)d_in[1];
  const float* b_qkv = (const float*)d_in[2];
  const float* th1   = (const float*)d_in[3];
  const float* th2   = (const float*)d_in[4];
  const float* w_out = (const float*)d_in[5];
  const float* b_out = (const float*)d_in[6];
  float* out = (float*)d_out;

  char* ws = (char*)d_ws;
  _Float16* Qh   = (_Float16*)(ws + QH_OFF);
  _Float16* Kh   = (_Float16*)(ws + KH_OFF);
  _Float16* Vt   = (_Float16*)(ws + VT_OFF);
  _Float16* Obuf = (_Float16*)(ws + O_OFF);
  if (ws_size < ((size_t)33 << 20)) return;  // need 33 MB scratch

  k_qkv  <<<dim3(128, 24), 256, 0, stream>>>(x, w_qkv, b_qkv, Qh, Kh, Vt);
  k_attn <<<dim3(512),     256, 0, stream>>>(Qh, Kh, Vt, th1, th2, Obuf);
  k_oproj<<<dim3(128, 8),  256, 0, stream>>>(Obuf, w_out, b_out, out);
}

// Round 10
// 437.605 us; speedup vs baseline: 1.2289x; 1.2289x over previous
//
#include <hip/hip_runtime.h>

typedef _Float16 half8  __attribute__((ext_vector_type(8)));
typedef _Float16 half4  __attribute__((ext_vector_type(4)));
typedef _Float16 half2v __attribute__((ext_vector_type(2)));
typedef float    f32x4  __attribute__((ext_vector_type(4)));

#define MFMA32(a,b,c) __builtin_amdgcn_mfma_f32_16x16x32_f16(a,b,c,0,0,0)
#define MFMA16(a,b,c) __builtin_amdgcn_mfma_f32_16x16x16f16(a,b,c,0,0,0)

#if __has_builtin(__builtin_amdgcn_exp2f)
#define EXP2F(x) __builtin_amdgcn_exp2f(x)
#else
#define EXP2F(x) exp2f(x)
#endif

// Async global->LDS, 16B per lane, dest = wave-uniform base + lane*16.
// Side-effecting intrinsic: compiler cannot sink/serialize it (R9 lesson).
// Every __syncthreads() drains vmcnt(0) -> staged data is landed after any barrier.
#define GLOAD16(gp, lp) __builtin_amdgcn_global_load_lds(                      \
    (const __attribute__((address_space(1))) void*)(gp),                       \
    (__attribute__((address_space(3))) void*)(lp), 16, 0, 0)

// scale = DH^-0.5 = 1/8, folded together with log2(e) into Q so softmax uses exp2.
static constexpr float SCALE_LOG2E = 0.18033688011112042f;

static constexpr size_t QH_OFF = 0;
static constexpr size_t KH_OFF = (size_t)8  << 20;
static constexpr size_t VT_OFF = (size_t)16 << 20;
static constexpr size_t O_OFF  = (size_t)24 << 20;

// ---------------------------------------------------------------------------
// K1: qkv projection. C[8192,1536] = X[8192,512] @ W[512,1536] + b.
// Scatters to Qh[b][h][n][64] (xSCALE_LOG2E), Kh[b][h][n][64], Vt[b][h][64][n], all f16.
// ---------------------------------------------------------------------------
__global__ __launch_bounds__(256)
void k_qkv(const float* __restrict__ x, const float* __restrict__ w,
           const float* __restrict__ bias, _Float16* __restrict__ Qh,
           _Float16* __restrict__ Kh, _Float16* __restrict__ Vt)
{
  __shared__ __align__(16) _Float16 Xs[64*40];
  __shared__ __align__(16) _Float16 Wt[64*40];
  const int tid = threadIdx.x;
  const int wv = tid >> 6, lane = tid & 63, l15 = lane & 15, qd = lane >> 4;
  const int row0 = blockIdx.x * 64, col0 = blockIdx.y * 64;

  const int xr = tid >> 2, xc = (tid & 3) * 8;
  const int wk = tid >> 3, wc = (tid & 7) * 8;

  f32x4 acc[4] = {{0.f,0.f,0.f,0.f},{0.f,0.f,0.f,0.f},{0.f,0.f,0.f,0.f},{0.f,0.f,0.f,0.f}};

  for (int k0 = 0; k0 < 512; k0 += 32) {
    f32x4 a0 = *(const f32x4*)(x + (size_t)(row0 + xr) * 512 + k0 + xc);
    f32x4 a1 = *(const f32x4*)(x + (size_t)(row0 + xr) * 512 + k0 + xc + 4);
    f32x4 b0 = *(const f32x4*)(w + (size_t)(k0 + wk) * 1536 + col0 + wc);
    f32x4 b1 = *(const f32x4*)(w + (size_t)(k0 + wk) * 1536 + col0 + wc + 4);
    half8 hx;
#pragma unroll
    for (int j = 0; j < 4; j++) { hx[j] = (_Float16)a0[j]; hx[j+4] = (_Float16)a1[j]; }
    *(half8*)&Xs[xr*40 + xc] = hx;
#pragma unroll
    for (int j = 0; j < 4; j++) {
      Wt[(wc+j  )*40 + wk] = (_Float16)b0[j];
      Wt[(wc+j+4)*40 + wk] = (_Float16)b1[j];
    }
    __syncthreads();
    half8 af = *(const half8*)&Xs[(wv*16 + l15)*40 + qd*8];
#pragma unroll
    for (int ct = 0; ct < 4; ct++) {
      half8 bf = *(const half8*)&Wt[(ct*16 + l15)*40 + qd*8];
      acc[ct] = MFMA32(af, bf, acc[ct]);
    }
    __syncthreads();
  }
#pragma unroll
  for (int ct = 0; ct < 4; ct++) {
    const int c = col0 + ct*16 + l15;
    const int sec = c >> 9, hh = (c >> 6) & 7, d = c & 63;
    const float bv = bias[c];
#pragma unroll
    for (int i = 0; i < 4; i++) {
      const int row = row0 + wv*16 + qd*4 + i;
      const int bb = row >> 11, n = row & 2047;
      float v = acc[ct][i] + bv;
      if (sec == 0)
        Qh[((size_t)((bb*8 + hh)*2048 + n))*64 + d] = (_Float16)(v * SCALE_LOG2E);
      else if (sec == 1)
        Kh[((size_t)((bb*8 + hh)*2048 + n))*64 + d] = (_Float16)v;
      else
        Vt[((size_t)((bb*8 + hh)*64 + d))*2048 + n] = (_Float16)v;
    }
  }
}

// ---------------------------------------------------------------------------
// K2: FUSED attention, async-staged. Grid 512 = 128nt x 4b, 16n rows/block,
// 4 waves. Wave wv owns: h-pair {2wv,2wv+1} (QK, Q hoisted in 16 VGPRs),
// G-pair {2wv,2wv+1} (mixes), g-pair {2wv,2wv+1} (PV). m-chunk 16/iter.
// K (4KB/wave) and V (4KB/wave) double-buffered via global_load_lds issued
// one barrier-segment ahead; barriers' vmcnt(0) drain guarantees landing.
// Sweep1: denominators -> nlgL (LDS). Sweep2: mix1(seeded)+exp2+mix2 -> Wb;
// PV; QK for it+1 in the same segment.
// ---------------------------------------------------------------------------
__global__ __launch_bounds__(256, 2)
void k_attn(const _Float16* __restrict__ Qh, const _Float16* __restrict__ Kh,
            const _Float16* __restrict__ Vt, const float* __restrict__ th1,
            const float* __restrict__ th2, _Float16* __restrict__ Obuf)
{
  __shared__ __align__(16) _Float16 KB[2][4][2048];  // 32768 B [buf][wv][2h x 16m x 64d, d8-swizzled]
  __shared__ __align__(16) _Float16 VB[2][4][2048];  // 32768 B [buf][wv][2g x 64d x 16m, m8-swizzled]
  __shared__ __align__(16) _Float16 Sb[2592];        //  5184 B [G8][col16 x20][k16]+pad
  __shared__ __align__(16) _Float16 Wb[2592];        //  5184 B [g8][n16 x20][m16]+pad
  __shared__ __align__(16) float nlgL[128];          //   512 B   (total ~76 KB -> 2 blocks/CU)
  const int tid = threadIdx.x;
  const int wv = tid >> 6, lane = tid & 63, l15 = lane & 15, qd = lane >> 4;
  const int b = blockIdx.x & 3, nt = blockIdx.x >> 2;
  const int n0 = nt << 4;

  const _Float16* kbase = Kh + (size_t)(b*8)*2048*64;
  const _Float16* vbase = Vt + (size_t)(b*8)*64*2048;

  // blockdiag A1 / B2 fragments for the 16x16x16 head-mix MFMAs (R6-verified)
  half4 a1f, b2f;
#pragma unroll
  for (int j = 0; j < 4; j++) {
    const bool diag = ((l15 >> 3) == (qd >> 1));
    a1f[j] = diag ? (_Float16)th1[(l15 & 7)*8 + (qd & 1)*4 + j] : (_Float16)0.f;
    b2f[j] = diag ? (_Float16)th2[(l15 & 7)*8 + (qd & 1)*4 + j] : (_Float16)0.f;
  }

  // hoisted Q B-frags for this wave's 2 heads (16 VGPRs -> stays resident)
  half8 qf[2][2];
#pragma unroll
  for (int hp = 0; hp < 2; hp++) {
    const _Float16* qp = Qh + ((size_t)((b*8 + 2*wv + hp)*2048 + n0 + l15))*64 + qd*8;
    qf[hp][0] = *(const half8*)qp;
    qf[hp][1] = *(const half8*)(qp + 32);
  }

  // ---- async stagers (wave-private regions; global-side XOR swizzles) ----
  auto issueK = [&](int it, int buf) {
    const int mmk = it*16;
    _Float16* lbase = &KB[buf][wv][0];
#pragma unroll
    for (int j = 0; j < 4; j++) {
      const int r  = j*8 + (lane >> 3);        // row (hp*16 + mrow)
      const int hp = r >> 4, mrow = r & 15;
      const int cp = (lane & 7) ^ (r & 7);     // swizzled 16B d-block
      const _Float16* g = kbase + ((size_t)((2*wv + hp)*2048 + mmk + mrow))*64 + cp*8;
      GLOAD16(g, lbase + j*512);
    }
  };
  auto issueV = [&](int it, int buf) {
    const int mmv = it*16;
    _Float16* lbase = &VB[buf][wv][0];
#pragma unroll
    for (int j = 0; j < 4; j++) {
      const int r  = j*32 + (lane >> 1);       // row (u*64 + d)
      const int u  = r >> 6, d = r & 63;
      const int cp = (lane & 1) ^ ((r >> 2) & 1);  // swizzled 16B m-block
      const _Float16* g = vbase + ((size_t)((2*wv + u)*64 + d))*2048 + mmv + cp*8;
      GLOAD16(g, lbase + j*512);
    }
  };
  // QK from staged K -> Sb (S for one 16m chunk; this wave's 2 heads)
  auto qk_to_sb = [&](int buf) {
    f32x4 acc[2];
#pragma unroll
    for (int hp = 0; hp < 2; hp++) {
      const int rr = hp*16 + l15;
      half8 ka0 = *(const half8*)&KB[buf][wv][rr*64 + ((qd     ^ (l15 & 7))*8)];
      half8 ka1 = *(const half8*)&KB[buf][wv][rr*64 + (((4+qd) ^ (l15 & 7))*8)];
      f32x4 a = {0.f,0.f,0.f,0.f};
      a = MFMA32(ka0, qf[hp][0], a);
      a = MFMA32(ka1, qf[hp][1], a);
      acc[hp] = a;
    }
#pragma unroll
    for (int i = 0; i < 4; i++) {
      half2v hv;
      hv[0] = (_Float16)acc[0][i];
      hv[1] = (_Float16)acc[1][i];
      *(half2v*)&Sb[(l15 >> 1)*324 + (qd*4 + i)*20 + 2*wv + 8*(l15 & 1)] = hv;
    }
  };

  // ================= Sweep 1: softmax denominators =================
  float lacc[2][4];
#pragma unroll
  for (int Gl = 0; Gl < 2; Gl++)
#pragma unroll
    for (int i = 0; i < 4; i++) lacc[Gl][i] = 0.f;

  issueK(0, 0);
  issueK(1, 1);
  __syncthreads();          // drain: K(0),K(1) landed
  qk_to_sb(0);              // S(0)
  __syncthreads();

  for (int it = 0; it < 128; it++) {
    // (b) mix1 + exp2 + accumulate for this wave's 2 G groups
#pragma unroll
    for (int Gl = 0; Gl < 2; Gl++) {
      const int G = 2*wv + Gl;
      half4 b1 = *(const half4*)&Sb[G*324 + l15*20 + qd*4];
      f32x4 c1 = MFMA16(a1f, b1, ((f32x4){0.f,0.f,0.f,0.f}));
#pragma unroll
      for (int i = 0; i < 4; i++) lacc[Gl][i] += EXP2F(c1[i]);
    }
    __syncthreads();
    // (a) prefetch K(it+2); compute S(it+1)
    if (it < 126) issueK(it + 2, it & 1);
    if (it < 127) qk_to_sb((it + 1) & 1);
    __syncthreads();
  }

  // reduce over the 16 m-columns (l15 lanes) and publish -log2(l)
#pragma unroll
  for (int Gl = 0; Gl < 2; Gl++)
#pragma unroll
    for (int i = 0; i < 4; i++) {
      float v = lacc[Gl][i];
      v += __shfl_xor(v, 1); v += __shfl_xor(v, 2);
      v += __shfl_xor(v, 4); v += __shfl_xor(v, 8);
      lacc[Gl][i] = v;
    }
  if (l15 == 0) {
#pragma unroll
    for (int Gl = 0; Gl < 2; Gl++)
#pragma unroll
      for (int i = 0; i < 4; i++) {
        const int n = (2*wv + Gl)*2 + (qd >> 1);
        const int g = (qd & 1)*4 + i;
        nlgL[n*8 + g] = -__log2f(lacc[Gl][i]);
      }
  }

  // ================= Sweep 2: PV =================
  f32x4 og[2][4];
#pragma unroll
  for (int u = 0; u < 2; u++)
#pragma unroll
    for (int dt = 0; dt < 4; dt++)
      og[u][dt] = (f32x4){0.f,0.f,0.f,0.f};

  issueK(0, 0); issueK(1, 1);
  issueV(0, 0); issueV(1, 1);
  __syncthreads();          // drain + nlgL visible
  qk_to_sb(0);              // S(0)
  __syncthreads();

  for (int it = 0; it < 128; it++) {
    // (b) mix1 (seeded with -log2 l in the C operand) -> exp2 -> mix2 -> Wb
#pragma unroll
    for (int Gl = 0; Gl < 2; Gl++) {
      const int G = 2*wv + Gl;
      half4 b1 = *(const half4*)&Sb[G*324 + l15*20 + qd*4];
      f32x4 cs = *(const f32x4*)&nlgL[(G*2 + (qd >> 1))*8 + (qd & 1)*4];
      f32x4 c1 = MFMA16(a1f, b1, cs);
      half4 a2;
#pragma unroll
      for (int i = 0; i < 4; i++) a2[i] = (_Float16)EXP2F(c1[i]);
      f32x4 c2 = MFMA16(a2, b2f, ((f32x4){0.f,0.f,0.f,0.f}));
      half4 w4;
#pragma unroll
      for (int i = 0; i < 4; i++) w4[i] = (_Float16)c2[i];
      *(half4*)&Wb[(l15 & 7)*324 + (G*2 + (l15 >> 3))*20 + qd*4] = w4;
    }
    __syncthreads();

    // (c1) prefetch K(it+2); PV from Wb + staged V; then prefetch V(it+2)
    if (it < 126) issueK(it + 2, it & 1);
    {
      const int buf = it & 1;
#pragma unroll
      for (int u = 0; u < 2; u++) {
        const int g = 2*wv + u;
        half4 af = *(const half4*)&Wb[g*324 + l15*20 + qd*4];
#pragma unroll
        for (int dt = 0; dt < 4; dt++) {
          const int rv = u*64 + dt*16 + l15;
          half4 bf = *(const half4*)&VB[buf][wv][rv*16 +
                      (((qd >> 1) ^ ((rv >> 2) & 1))*8) + (qd & 1)*4];
          og[u][dt] = MFMA16(af, bf, og[u][dt]);
        }
      }
    }
    if (it < 126) issueV(it + 2, it & 1);   // after V reads: no buffer clash
    // (c2) compute S(it+1) from staged K
    if (it < 127) qk_to_sb((it + 1) & 1);
    __syncthreads();
  }

  // epilogue: og[u][dt][i] -> (n = n0+qd*4+i, col = (2wv+u)*64 + dt*16 + l15)
  _Float16* Op = Obuf + ((size_t)(b*2048 + n0))*512;
#pragma unroll
  for (int u = 0; u < 2; u++)
#pragma unroll
    for (int dt = 0; dt < 4; dt++)
#pragma unroll
      for (int i = 0; i < 4; i++)
        Op[(size_t)(qd*4 + i)*512 + (2*wv + u)*64 + dt*16 + l15] = (_Float16)og[u][dt][i];
}

// ---------------------------------------------------------------------------
// K3: output projection. out[8192,512] = Obuf @ w_out[512,512] + b_out (fp32)
// ---------------------------------------------------------------------------
__global__ __launch_bounds__(256)
void k_oproj(const _Float16* __restrict__ Ob, const float* __restrict__ w,
             const float* __restrict__ bias, float* __restrict__ out)
{
  __shared__ __align__(16) _Float16 Xs[64*40];
  __shared__ __align__(16) _Float16 Wt[64*40];
  const int tid = threadIdx.x;
  const int wv = tid >> 6, lane = tid & 63, l15 = lane & 15, qd = lane >> 4;
  const int row0 = blockIdx.x * 64, col0 = blockIdx.y * 64;
  const int xr = tid >> 2, xc = (tid & 3) * 8;
  const int wk = tid >> 3, wc = (tid & 7) * 8;

  f32x4 acc[4] = {{0.f,0.f,0.f,0.f},{0.f,0.f,0.f,0.f},{0.f,0.f,0.f,0.f},{0.f,0.f,0.f,0.f}};

  for (int k0 = 0; k0 < 512; k0 += 32) {
    *(half8*)&Xs[xr*40 + xc] = *(const half8*)(Ob + (size_t)(row0 + xr)*512 + k0 + xc);
    f32x4 b0 = *(const f32x4*)(w + (size_t)(k0 + wk)*512 + col0 + wc);
    f32x4 b1 = *(const f32x4*)(w + (size_t)(k0 + wk)*512 + col0 + wc + 4);
#pragma unroll
    for (int j = 0; j < 4; j++) {
      Wt[(wc+j  )*40 + wk] = (_Float16)b0[j];
      Wt[(wc+j+4)*40 + wk] = (_Float16)b1[j];
    }
    __syncthreads();
    half8 af = *(const half8*)&Xs[(wv*16 + l15)*40 + qd*8];
#pragma unroll
    for (int ct = 0; ct < 4; ct++) {
      half8 bf = *(const half8*)&Wt[(ct*16 + l15)*40 + qd*8];
      acc[ct] = MFMA32(af, bf, acc[ct]);
    }
    __syncthreads();
  }
#pragma unroll
  for (int ct = 0; ct < 4; ct++) {
    const int c = col0 + ct*16 + l15;
    const float bv = bias[c];
#pragma unroll
    for (int i = 0; i < 4; i++) {
      const int row = row0 + wv*16 + qd*4 + i;
      out[(size_t)row*512 + c] = acc[ct][i] + bv;
    }
  }
}

// ---------------------------------------------------------------------------
extern "C" void kernel_launch(void* const* d_in, const int* in_sizes, int n_in,
                              void* d_out, int out_size, void* d_ws, size_t ws_size,
                              hipStream_t stream)
{
  (void)in_sizes; (void)n_in; (void)out_size;
  const float* x     = (const float*)d_in[0];
  const float* w_qkv = (const float*)d_in[1];
  const float* b_qkv = (const float*)d_in[2];
  const float* th1   = (const float*)d_in[3];
  const float* th2   = (const float*)d_in[4];
  const float* w_out = (const float*)d_in[5];
  const float* b_out = (const float*)d_in[6];
  float* out = (float*)d_out;

  char* ws = (char*)d_ws;
  _Float16* Qh   = (_Float16*)(ws + QH_OFF);
  _Float16* Kh   = (_Float16*)(ws + KH_OFF);
  _Float16* Vt   = (_Float16*)(ws + VT_OFF);
  _Float16* Obuf = (_Float16*)(ws + O_OFF);
  if (ws_size < ((size_t)33 << 20)) return;  // need 33 MB scratch

  k_qkv  <<<dim3(128, 24), 256, 0, stream>>>(x, w_qkv, b_qkv, Qh, Kh, Vt);
  k_attn <<<dim3(512),     256, 0, stream>>>(Qh, Kh, Vt, th1, th2, Obuf);
  k_oproj<<<dim3(128, 8),  256, 0, stream>>>(Obuf, w_out, b_out, out);
}

// Round 11
// 413.210 us; speedup vs baseline: 1.3014x; 1.0590x over previous
//
#include <hip/hip_runtime.h>

typedef _Float16 half8  __attribute__((ext_vector_type(8)));
typedef _Float16 half4  __attribute__((ext_vector_type(4)));
typedef float    f32x4  __attribute__((ext_vector_type(4)));

#define MFMA32(a,b,c) __builtin_amdgcn_mfma_f32_16x16x32_f16(a,b,c,0,0,0)
#define MFMA16(a,b,c) __builtin_amdgcn_mfma_f32_16x16x16f16(a,b,c,0,0,0)

#if __has_builtin(__builtin_amdgcn_exp2f)
#define EXP2F(x) __builtin_amdgcn_exp2f(x)
#else
#define EXP2F(x) exp2f(x)
#endif

// Async global->LDS, 16B/lane, dest = wave-uniform base + lane*16.
// Side-effecting: compiler cannot sink it (R9/R10 lesson). __syncthreads()
// drains vmcnt(0) -> anything issued before a barrier is landed after it.
#define GLOAD16(gp, lp) __builtin_amdgcn_global_load_lds(                      \
    (const __attribute__((address_space(1))) void*)(gp),                       \
    (__attribute__((address_space(3))) void*)(lp), 16, 0, 0)

// scale = DH^-0.5 = 1/8, folded together with log2(e) into Q so softmax uses exp2.
static constexpr float SCALE_LOG2E = 0.18033688011112042f;

static constexpr size_t QH_OFF = 0;
static constexpr size_t KH_OFF = (size_t)8  << 20;
static constexpr size_t VT_OFF = (size_t)16 << 20;
static constexpr size_t O_OFF  = (size_t)24 << 20;

// ---------------------------------------------------------------------------
// K1: qkv projection. C[8192,1536] = X[8192,512] @ W[512,1536] + b.
// Scatters to Qh[b][h][n][64] (xSCALE_LOG2E), Kh[b][h][n][64], Vt[b][h][64][n], all f16.
// ---------------------------------------------------------------------------
__global__ __launch_bounds__(256)
void k_qkv(const float* __restrict__ x, const float* __restrict__ w,
           const float* __restrict__ bias, _Float16* __restrict__ Qh,
           _Float16* __restrict__ Kh, _Float16* __restrict__ Vt)
{
  __shared__ __align__(16) _Float16 Xs[64*40];
  __shared__ __align__(16) _Float16 Wt[64*40];
  const int tid = threadIdx.x;
  const int wv = tid >> 6, lane = tid & 63, l15 = lane & 15, qd = lane >> 4;
  const int row0 = blockIdx.x * 64, col0 = blockIdx.y * 64;

  const int xr = tid >> 2, xc = (tid & 3) * 8;
  const int wk = tid >> 3, wc = (tid & 7) * 8;

  f32x4 acc[4] = {{0.f,0.f,0.f,0.f},{0.f,0.f,0.f,0.f},{0.f,0.f,0.f,0.f},{0.f,0.f,0.f,0.f}};

  for (int k0 = 0; k0 < 512; k0 += 32) {
    f32x4 a0 = *(const f32x4*)(x + (size_t)(row0 + xr) * 512 + k0 + xc);
    f32x4 a1 = *(const f32x4*)(x + (size_t)(row0 + xr) * 512 + k0 + xc + 4);
    f32x4 b0 = *(const f32x4*)(w + (size_t)(k0 + wk) * 1536 + col0 + wc);
    f32x4 b1 = *(const f32x4*)(w + (size_t)(k0 + wk) * 1536 + col0 + wc + 4);
    half8 hx;
#pragma unroll
    for (int j = 0; j < 4; j++) { hx[j] = (_Float16)a0[j]; hx[j+4] = (_Float16)a1[j]; }
    *(half8*)&Xs[xr*40 + xc] = hx;
#pragma unroll
    for (int j = 0; j < 4; j++) {
      Wt[(wc+j  )*40 + wk] = (_Float16)b0[j];
      Wt[(wc+j+4)*40 + wk] = (_Float16)b1[j];
    }
    __syncthreads();
    half8 af = *(const half8*)&Xs[(wv*16 + l15)*40 + qd*8];
#pragma unroll
    for (int ct = 0; ct < 4; ct++) {
      half8 bf = *(const half8*)&Wt[(ct*16 + l15)*40 + qd*8];
      acc[ct] = MFMA32(af, bf, acc[ct]);
    }
    __syncthreads();
  }
#pragma unroll
  for (int ct = 0; ct < 4; ct++) {
    const int c = col0 + ct*16 + l15;
    const int sec = c >> 9, hh = (c >> 6) & 7, d = c & 63;
    const float bv = bias[c];
#pragma unroll
    for (int i = 0; i < 4; i++) {
      const int row = row0 + wv*16 + qd*4 + i;
      const int bb = row >> 11, n = row & 2047;
      float v = acc[ct][i] + bv;
      if (sec == 0)
        Qh[((size_t)((bb*8 + hh)*2048 + n))*64 + d] = (_Float16)(v * SCALE_LOG2E);
      else if (sec == 1)
        Kh[((size_t)((bb*8 + hh)*2048 + n))*64 + d] = (_Float16)v;
      else
        Vt[((size_t)((bb*8 + hh)*64 + d))*2048 + n] = (_Float16)v;
    }
  }
}

// ---------------------------------------------------------------------------
// K2: FUSED attention. Grid 512 = 128nt x 4b, BLOCK = 512 threads (8 waves).
// Wave w owns: head h=w (QK, Q hoisted: 8 VGPRs), group G=w (mixes),
// g=w (PV, og: 16 VGPRs). m-chunk 16/iter, 128 iters/sweep.
// ONE barrier per iteration: [QK(it)->Sb[p]; issueK(it+1); mix(it-1)->Wb;
// PV(it-2) + issueV(it-1)] ; __syncthreads. Sb/Wb double-buffered (cross-wave
// handoffs cross exactly one barrier); KB/VB single, wave-private (WAR is
// in-wave: reads precede the overwrite-issue in program order).
// 54 KB LDS -> 2 blocks/CU = 16 waves/CU: one block's vmcnt drain overlaps
// the other block's compute.
// ---------------------------------------------------------------------------
__global__ __launch_bounds__(512, 4)
void k_attn(const _Float16* __restrict__ Qh, const _Float16* __restrict__ Kh,
            const _Float16* __restrict__ Vt, const float* __restrict__ th1,
            const float* __restrict__ th2, _Float16* __restrict__ Obuf)
{
  __shared__ __align__(16) _Float16 KB[8][1024];   // 16384 B [wv][16m x 64d, d8-swizzled]
  __shared__ __align__(16) _Float16 VB[8][1024];   // 16384 B [wv][64d x 16m, m8-swizzled]
  __shared__ __align__(16) _Float16 Sb[2][2592];   // 10368 B [G8][col16 x20][k16]
  __shared__ __align__(16) _Float16 Wb[2][2592];   // 10368 B [g8][n16 x20][m16]
  __shared__ __align__(16) float nlgL[128];        //   512 B  (total 54016 B)
  const int tid = threadIdx.x;
  const int wv = tid >> 6, lane = tid & 63, l15 = lane & 15, qd = lane >> 4;
  const int b = blockIdx.x & 3, nt = blockIdx.x >> 2;
  const int n0 = nt << 4;

  const _Float16* kbase = Kh + (size_t)(b*8 + wv)*2048*64;  // this wave's head
  const _Float16* vbase = Vt + (size_t)(b*8 + wv)*64*2048;

  // blockdiag A1 / B2 fragments for the 16x16x16 head-mix MFMAs (R6-verified)
  half4 a1f, b2f;
#pragma unroll
  for (int j = 0; j < 4; j++) {
    const bool diag = ((l15 >> 3) == (qd >> 1));
    a1f[j] = diag ? (_Float16)th1[(l15 & 7)*8 + (qd & 1)*4 + j] : (_Float16)0.f;
    b2f[j] = diag ? (_Float16)th2[(l15 & 7)*8 + (qd & 1)*4 + j] : (_Float16)0.f;
  }

  // hoisted Q B-frag for this wave's head (8 VGPRs)
  half8 qf0, qf1;
  {
    const _Float16* qp = Qh + ((size_t)((b*8 + wv)*2048 + n0 + l15))*64 + qd*8;
    qf0 = *(const half8*)qp;
    qf1 = *(const half8*)(qp + 32);
  }

  // ---- async stagers (wave-private; global-side XOR swizzles) ----
  auto issueK = [&](int it) {
    const int mmk = it*16;
#pragma unroll
    for (int j = 0; j < 2; j++) {
      const int bk = j*64 + lane;            // 16B block index 0..127
      const int m = bk >> 3, c = bk & 7;
      const int cp = c ^ (m & 7);            // swizzled global d-block
      const _Float16* g = kbase + ((size_t)(mmk + m))*64 + cp*8;
      GLOAD16(g, &KB[wv][j*512]);
    }
  };
  auto issueV = [&](int it) {
    const int mmv = it*16;
#pragma unroll
    for (int j = 0; j < 2; j++) {
      const int bk = j*64 + lane;
      const int d = bk >> 1, c = bk & 1;
      const int cp = c ^ ((d >> 2) & 1);     // swizzled global m-halfrow
      const _Float16* g = vbase + (size_t)d*2048 + mmv + cp*8;
      GLOAD16(g, &VB[wv][j*512]);
    }
  };
  // QK from staged K -> Sb[buf] (S for one 16m chunk, this wave's head)
  auto qk_to_sb = [&](int buf) {
    half8 ka0 = *(const half8*)&KB[wv][l15*64 + ((qd       ^ (l15 & 7))*8)];
    half8 ka1 = *(const half8*)&KB[wv][l15*64 + (((4 + qd) ^ (l15 & 7))*8)];
    f32x4 a = {0.f,0.f,0.f,0.f};
    a = MFMA32(ka0, qf0, a);
    a = MFMA32(ka1, qf1, a);
#pragma unroll
    for (int i = 0; i < 4; i++)
      Sb[buf][(l15 >> 1)*324 + (qd*4 + i)*20 + wv + 8*(l15 & 1)] = (_Float16)a[i];
  };

  // ================= Sweep 1: softmax denominators =================
  float lacc[4] = {0.f, 0.f, 0.f, 0.f};

  issueK(0);
  __syncthreads();
  for (int it = 0; it <= 128; it++) {
    if (it < 128) {
      qk_to_sb(it & 1);
      if (it + 1 < 128) issueK(it + 1);
    }
    if (it >= 1) {
      half4 b1 = *(const half4*)&Sb[(it - 1) & 1][wv*324 + l15*20 + qd*4];
      f32x4 c1 = MFMA16(a1f, b1, ((f32x4){0.f,0.f,0.f,0.f}));
#pragma unroll
      for (int i = 0; i < 4; i++) lacc[i] += EXP2F(c1[i]);
    }
    __syncthreads();
  }

  // reduce over the 16 m-columns (l15 lanes) and publish -log2(l)
#pragma unroll
  for (int i = 0; i < 4; i++) {
    float v = lacc[i];
    v += __shfl_xor(v, 1); v += __shfl_xor(v, 2);
    v += __shfl_xor(v, 4); v += __shfl_xor(v, 8);
    lacc[i] = v;
  }
  if (l15 == 0) {
#pragma unroll
    for (int i = 0; i < 4; i++) {
      const int n = wv*2 + (qd >> 1);
      const int g = (qd & 1)*4 + i;
      nlgL[n*8 + g] = -__log2f(lacc[i]);
    }
  }

  // ================= Sweep 2: PV =================
  f32x4 og[4];
#pragma unroll
  for (int dt = 0; dt < 4; dt++) og[dt] = (f32x4){0.f,0.f,0.f,0.f};

  issueK(0);
  issueV(0);
  __syncthreads();          // drains K(0),V(0); nlgL visible

  for (int it = 0; it <= 129; it++) {
    if (it < 128) {
      qk_to_sb(it & 1);
      if (it + 1 < 128) issueK(it + 1);
    }
    if (it >= 1 && it <= 128) {
      const int buf = (it - 1) & 1;
      half4 b1 = *(const half4*)&Sb[buf][wv*324 + l15*20 + qd*4];
      f32x4 cs = *(const f32x4*)&nlgL[(wv*2 + (qd >> 1))*8 + (qd & 1)*4];
      f32x4 c1 = MFMA16(a1f, b1, cs);
      half4 a2;
#pragma unroll
      for (int i = 0; i < 4; i++) a2[i] = (_Float16)EXP2F(c1[i]);
      f32x4 c2 = MFMA16(a2, b2f, ((f32x4){0.f,0.f,0.f,0.f}));
      half4 w4;
#pragma unroll
      for (int i = 0; i < 4; i++) w4[i] = (_Float16)c2[i];
      *(half4*)&Wb[buf][(l15 & 7)*324 + (wv*2 + (l15 >> 3))*20 + qd*4] = w4;
    }
    if (it >= 2) {
      const int buf = (it - 2) & 1;
      half4 af = *(const half4*)&Wb[buf][wv*324 + l15*20 + qd*4];
#pragma unroll
      for (int dt = 0; dt < 4; dt++) {
        const int rv = dt*16 + l15;
        half4 bf = *(const half4*)&VB[wv][rv*16 +
                    (((qd >> 1) ^ ((rv >> 2) & 1))*8) + (qd & 1)*4];
        og[dt] = MFMA16(af, bf, og[dt]);
      }
      if (it - 1 < 128) issueV(it - 1);
    }
    __syncthreads();
  }

  // epilogue: og[dt][i] -> (n = n0+qd*4+i, col = wv*64 + dt*16 + l15)
  _Float16* Op = Obuf + ((size_t)(b*2048 + n0))*512;
#pragma unroll
  for (int dt = 0; dt < 4; dt++)
#pragma unroll
    for (int i = 0; i < 4; i++)
      Op[(size_t)(qd*4 + i)*512 + wv*64 + dt*16 + l15] = (_Float16)og[dt][i];
}

// ---------------------------------------------------------------------------
// K3: output projection. out[8192,512] = Obuf @ w_out[512,512] + b_out (fp32)
// ---------------------------------------------------------------------------
__global__ __launch_bounds__(256)
void k_oproj(const _Float16* __restrict__ Ob, const float* __restrict__ w,
             const float* __restrict__ bias, float* __restrict__ out)
{
  __shared__ __align__(16) _Float16 Xs[64*40];
  __shared__ __align__(16) _Float16 Wt[64*40];
  const int tid = threadIdx.x;
  const int wv = tid >> 6, lane = tid & 63, l15 = lane & 15, qd = lane >> 4;
  const int row0 = blockIdx.x * 64, col0 = blockIdx.y * 64;
  const int xr = tid >> 2, xc = (tid & 3) * 8;
  const int wk = tid >> 3, wc = (tid & 7) * 8;

  f32x4 acc[4] = {{0.f,0.f,0.f,0.f},{0.f,0.f,0.f,0.f},{0.f,0.f,0.f,0.f},{0.f,0.f,0.f,0.f}};

  for (int k0 = 0; k0 < 512; k0 += 32) {
    *(half8*)&Xs[xr*40 + xc] = *(const half8*)(Ob + (size_t)(row0 + xr)*512 + k0 + xc);
    f32x4 b0 = *(const f32x4*)(w + (size_t)(k0 + wk)*512 + col0 + wc);
    f32x4 b1 = *(const f32x4*)(w + (size_t)(k0 + wk)*512 + col0 + wc + 4);
#pragma unroll
    for (int j = 0; j < 4; j++) {
      Wt[(wc+j  )*40 + wk] = (_Float16)b0[j];
      Wt[(wc+j+4)*40 + wk] = (_Float16)b1[j];
    }
    __syncthreads();
    half8 af = *(const half8*)&Xs[(wv*16 + l15)*40 + qd*8];
#pragma unroll
    for (int ct = 0; ct < 4; ct++) {
      half8 bf = *(const half8*)&Wt[(ct*16 + l15)*40 + qd*8];
      acc[ct] = MFMA32(af, bf, acc[ct]);
    }
    __syncthreads();
  }
#pragma unroll
  for (int ct = 0; ct < 4; ct++) {
    const int c = col0 + ct*16 + l15;
    const float bv = bias[c];
#pragma unroll
    for (int i = 0; i < 4; i++) {
      const int row = row0 + wv*16 + qd*4 + i;
      out[(size_t)row*512 + c] = acc[ct][i] + bv;
    }
  }
}

// ---------------------------------------------------------------------------
extern "C" void kernel_launch(void* const* d_in, const int* in_sizes, int n_in,
                              void* d_out, int out_size, void* d_ws, size_t ws_size,
                              hipStream_t stream)
{
  (void)in_sizes; (void)n_in; (void)out_size;
  const float* x     = (const float*)d_in[0];
  const float* w_qkv = (const float*)d_in[1];
  const float* b_qkv = (const float*)d_in[2];
  const float* th1   = (const float*)d_in[3];
  const float* th2   = (const float*)d_in[4];
  const float* w_out = (const float*)d_in[5];
  const float* b_out = (const float*)d_in[6];
  float* out = (float*)d_out;

  char* ws = (char*)d_ws;
  _Float16* Qh   = (_Float16*)(ws + QH_OFF);
  _Float16* Kh   = (_Float16*)(ws + KH_OFF);
  _Float16* Vt   = (_Float16*)(ws + VT_OFF);
  _Float16* Obuf = (_Float16*)(ws + O_OFF);
  if (ws_size < ((size_t)33 << 20)) return;  // need 33 MB scratch

  k_qkv  <<<dim3(128, 24), 256, 0, stream>>>(x, w_qkv, b_qkv, Qh, Kh, Vt);
  k_attn <<<dim3(512),     512, 0, stream>>>(Qh, Kh, Vt, th1, th2, Obuf);
  k_oproj<<<dim3(128, 8),  256, 0, stream>>>(Obuf, w_out, b_out, out);
}

// Round 12
// 351.864 us; speedup vs baseline: 1.5283x; 1.1743x over previous
//
#include <hip/hip_runtime.h>

typedef _Float16 half8  __attribute__((ext_vector_type(8)));
typedef _Float16 half4  __attribute__((ext_vector_type(4)));
typedef float    f32x4  __attribute__((ext_vector_type(4)));

#define MFMA32(a,b,c) __builtin_amdgcn_mfma_f32_16x16x32_f16(a,b,c,0,0,0)
#define MFMA16(a,b,c) __builtin_amdgcn_mfma_f32_16x16x16f16(a,b,c,0,0,0)

#if __has_builtin(__builtin_amdgcn_exp2f)
#define EXP2F(x) __builtin_amdgcn_exp2f(x)
#else
#define EXP2F(x) exp2f(x)
#endif

// Async global->LDS, 16B/lane, dest = wave-uniform base + lane*16.
// Side-effecting: compiler cannot sink it. __syncthreads() drains vmcnt(0).
#define GLOAD16(gp, lp) __builtin_amdgcn_global_load_lds(                      \
    (const __attribute__((address_space(1))) void*)(gp),                       \
    (__attribute__((address_space(3))) void*)(lp), 16, 0, 0)

// scale = DH^-0.5 = 1/8, folded together with log2(e) into Q so softmax uses exp2.
static constexpr float SCALE_LOG2E = 0.18033688011112042f;

static constexpr size_t QH_OFF = 0;
static constexpr size_t KH_OFF = (size_t)8  << 20;
static constexpr size_t VT_OFF = (size_t)16 << 20;
static constexpr size_t LS_OFF = (size_t)24 << 20;
static constexpr size_t O_OFF  = (size_t)25 << 20;
static constexpr size_t LPART  = (size_t)4*8*2048;   // floats per m-half L partial
static constexpr size_t OPART  = (size_t)8192*512;   // halves per O partial

// ---------------------------------------------------------------------------
// K1: qkv projection. C[8192,1536] = X[8192,512] @ W[512,1536] + b.
// Scatters to Qh[b][h][n][64] (xSCALE_LOG2E), Kh[b][h][n][64], Vt[b][h][64][n], all f16.
// ---------------------------------------------------------------------------
__global__ __launch_bounds__(256)
void k_qkv(const float* __restrict__ x, const float* __restrict__ w,
           const float* __restrict__ bias, _Float16* __restrict__ Qh,
           _Float16* __restrict__ Kh, _Float16* __restrict__ Vt)
{
  __shared__ __align__(16) _Float16 Xs[64*40];
  __shared__ __align__(16) _Float16 Wt[64*40];
  const int tid = threadIdx.x;
  const int wv = tid >> 6, lane = tid & 63, l15 = lane & 15, qd = lane >> 4;
  const int row0 = blockIdx.x * 64, col0 = blockIdx.y * 64;

  const int xr = tid >> 2, xc = (tid & 3) * 8;
  const int wk = tid >> 3, wc = (tid & 7) * 8;

  f32x4 acc[4] = {{0.f,0.f,0.f,0.f},{0.f,0.f,0.f,0.f},{0.f,0.f,0.f,0.f},{0.f,0.f,0.f,0.f}};

  for (int k0 = 0; k0 < 512; k0 += 32) {
    f32x4 a0 = *(const f32x4*)(x + (size_t)(row0 + xr) * 512 + k0 + xc);
    f32x4 a1 = *(const f32x4*)(x + (size_t)(row0 + xr) * 512 + k0 + xc + 4);
    f32x4 b0 = *(const f32x4*)(w + (size_t)(k0 + wk) * 1536 + col0 + wc);
    f32x4 b1 = *(const f32x4*)(w + (size_t)(k0 + wk) * 1536 + col0 + wc + 4);
    half8 hx;
#pragma unroll
    for (int j = 0; j < 4; j++) { hx[j] = (_Float16)a0[j]; hx[j+4] = (_Float16)a1[j]; }
    *(half8*)&Xs[xr*40 + xc] = hx;
#pragma unroll
    for (int j = 0; j < 4; j++) {
      Wt[(wc+j  )*40 + wk] = (_Float16)b0[j];
      Wt[(wc+j+4)*40 + wk] = (_Float16)b1[j];
    }
    __syncthreads();
    half8 af = *(const half8*)&Xs[(wv*16 + l15)*40 + qd*8];
#pragma unroll
    for (int ct = 0; ct < 4; ct++) {
      half8 bf = *(const half8*)&Wt[(ct*16 + l15)*40 + qd*8];
      acc[ct] = MFMA32(af, bf, acc[ct]);
    }
    __syncthreads();
  }
#pragma unroll
  for (int ct = 0; ct < 4; ct++) {
    const int c = col0 + ct*16 + l15;
    const int sec = c >> 9, hh = (c >> 6) & 7, d = c & 63;
    const float bv = bias[c];
#pragma unroll
    for (int i = 0; i < 4; i++) {
      const int row = row0 + wv*16 + qd*4 + i;
      const int bb = row >> 11, n = row & 2047;
      float v = acc[ct][i] + bv;
      if (sec == 0)
        Qh[((size_t)((bb*8 + hh)*2048 + n))*64 + d] = (_Float16)(v * SCALE_LOG2E);
      else if (sec == 1)
        Kh[((size_t)((bb*8 + hh)*2048 + n))*64 + d] = (_Float16)v;
      else
        Vt[((size_t)((bb*8 + hh)*64 + d))*2048 + n] = (_Float16)v;
    }
  }
}

// ---------------------------------------------------------------------------
// K2: pass 1 — softmax denominators over an m-half. Grid 512 = 64nt x (4b x 2mh),
// blockIdx = nt*8 + b*2 + mh (each XCD owns one (b,mh): 1 MB K slice in L2).
// Block = 512 threads (8 waves), 32 n-rows (2 tiles). Wave w: head h=w (QK),
// n-pair G=w (mix). K/V LDS reads amortized over both n-tiles (R11 lesson:
// LDS pipe is the bottleneck — ops per unit work halved).
// ---------------------------------------------------------------------------
__global__ __launch_bounds__(512, 4)
void k_pass1(const _Float16* __restrict__ Qh, const _Float16* __restrict__ Kh,
             const float* __restrict__ th1, float* __restrict__ Lsum)
{
  __shared__ __align__(16) _Float16 KB[8][1024];     // 16384 B [wv][16m x 64d, d8-swz]
  __shared__ __align__(16) _Float16 Sb[2][2][2592];  // 20736 B [buf][tile]
  const int tid = threadIdx.x;
  const int wv = tid >> 6, lane = tid & 63, l15 = lane & 15, qd = lane >> 4;
  const int s = blockIdx.x & 7, nt = blockIdx.x >> 3;
  const int b = s >> 1, mh = s & 1;
  const int n0 = nt << 5;
  const _Float16* kbase = Kh + ((size_t)((b*8 + wv)*2048 + mh*1024))*64;

  half4 a1f;
#pragma unroll
  for (int j = 0; j < 4; j++)
    a1f[j] = ((l15 >> 3) == (qd >> 1)) ? (_Float16)th1[(l15 & 7)*8 + (qd & 1)*4 + j]
                                       : (_Float16)0.f;

  half8 qf[2][2];
#pragma unroll
  for (int t = 0; t < 2; t++) {
    const _Float16* qp = Qh + ((size_t)((b*8 + wv)*2048 + n0 + t*16 + l15))*64 + qd*8;
    qf[t][0] = *(const half8*)qp;
    qf[t][1] = *(const half8*)(qp + 32);
  }

  auto issueK = [&](int it) {
#pragma unroll
    for (int j = 0; j < 2; j++) {
      const int bk = j*64 + lane;
      const int m = bk >> 3, c = bk & 7;
      const int cp = c ^ (m & 7);
      GLOAD16(kbase + (size_t)(it*16 + m)*64 + cp*8, &KB[wv][j*512]);
    }
  };
  auto qk_to_sb = [&](int buf) {
    half8 ka0 = *(const half8*)&KB[wv][l15*64 + ((qd       ^ (l15 & 7))*8)];
    half8 ka1 = *(const half8*)&KB[wv][l15*64 + (((4 + qd) ^ (l15 & 7))*8)];
#pragma unroll
    for (int t = 0; t < 2; t++) {
      f32x4 a = {0.f,0.f,0.f,0.f};
      a = MFMA32(ka0, qf[t][0], a);
      a = MFMA32(ka1, qf[t][1], a);
#pragma unroll
      for (int i = 0; i < 4; i++)
        Sb[buf][t][(l15 >> 1)*324 + (qd*4 + i)*20 + wv + 8*(l15 & 1)] = (_Float16)a[i];
    }
  };

  float lacc[2][4];
#pragma unroll
  for (int t = 0; t < 2; t++)
#pragma unroll
    for (int i = 0; i < 4; i++) lacc[t][i] = 0.f;

  issueK(0);
  __syncthreads();
  for (int it = 0; it <= 64; it++) {
    if (it < 64) {
      qk_to_sb(it & 1);
      if (it + 1 < 64) issueK(it + 1);
    }
    if (it >= 1) {
      const int buf = (it - 1) & 1;
#pragma unroll
      for (int t = 0; t < 2; t++) {
        half4 b1 = *(const half4*)&Sb[buf][t][wv*324 + l15*20 + qd*4];
        f32x4 c1 = MFMA16(a1f, b1, ((f32x4){0.f,0.f,0.f,0.f}));
#pragma unroll
        for (int i = 0; i < 4; i++) lacc[t][i] += EXP2F(c1[i]);
      }
    }
    __syncthreads();
  }

#pragma unroll
  for (int t = 0; t < 2; t++)
#pragma unroll
    for (int i = 0; i < 4; i++) {
      float v = lacc[t][i];
      v += __shfl_xor(v, 1); v += __shfl_xor(v, 2);
      v += __shfl_xor(v, 4); v += __shfl_xor(v, 8);
      lacc[t][i] = v;
    }
  if (l15 == 0) {
#pragma unroll
    for (int t = 0; t < 2; t++)
#pragma unroll
      for (int i = 0; i < 4; i++) {
        const int n = n0 + t*16 + wv*2 + (qd >> 1);
        const int g = (qd & 1)*4 + i;
        Lsum[(size_t)mh*LPART + (size_t)(b*8 + g)*2048 + n] = lacc[t][i];
      }
  }
}

// ---------------------------------------------------------------------------
// K3: pass 2 over an m-half. Same decomposition as pass 1 + PV.
// Seed -log2(l partial-sum) hoisted to REGISTERS (per-lane constant).
// Pipeline (1 barrier/iter): [QK(it)->Sb; issueK(it+1); mix(it-1)->Wb;
// PV(it-2) (VB reads shared across tiles); issueV(it-1)]; barrier.
// O written as per-mh partial; k_oproj sums 2.
// ---------------------------------------------------------------------------
__global__ __launch_bounds__(512, 4)
void k_pass2(const _Float16* __restrict__ Qh, const _Float16* __restrict__ Kh,
             const _Float16* __restrict__ Vt, const float* __restrict__ Lsum,
             const float* __restrict__ th1, const float* __restrict__ th2,
             _Float16* __restrict__ Obuf)
{
  __shared__ __align__(16) _Float16 KB[8][1024];     // 16384 B
  __shared__ __align__(16) _Float16 VB[8][1024];     // 16384 B [wv][64d x 16m, m8-swz]
  __shared__ __align__(16) _Float16 Sb[2][2][2592];  // 20736 B
  __shared__ __align__(16) _Float16 Wb[2][2][2592];  // 20736 B  (total 74240 B)
  const int tid = threadIdx.x;
  const int wv = tid >> 6, lane = tid & 63, l15 = lane & 15, qd = lane >> 4;
  const int s = blockIdx.x & 7, nt = blockIdx.x >> 3;
  const int b = s >> 1, mh = s & 1;
  const int n0 = nt << 5;
  const _Float16* kbase = Kh + ((size_t)((b*8 + wv)*2048 + mh*1024))*64;
  const _Float16* vbase = Vt + (size_t)(b*8 + wv)*64*2048 + mh*1024;

  half4 a1f, b2f;
#pragma unroll
  for (int j = 0; j < 4; j++) {
    const bool diag = ((l15 >> 3) == (qd >> 1));
    a1f[j] = diag ? (_Float16)th1[(l15 & 7)*8 + (qd & 1)*4 + j] : (_Float16)0.f;
    b2f[j] = diag ? (_Float16)th2[(l15 & 7)*8 + (qd & 1)*4 + j] : (_Float16)0.f;
  }

  // softmax seed, hoisted to registers (constant per lane across all iters)
  f32x4 cs[2];
#pragma unroll
  for (int t = 0; t < 2; t++)
#pragma unroll
    for (int i = 0; i < 4; i++) {
      const int n = n0 + t*16 + wv*2 + (qd >> 1);
      const int g = (qd & 1)*4 + i;
      const size_t off = (size_t)(b*8 + g)*2048 + n;
      cs[t][i] = -__log2f(Lsum[off] + Lsum[off + LPART]);
    }

  half8 qf[2][2];
#pragma unroll
  for (int t = 0; t < 2; t++) {
    const _Float16* qp = Qh + ((size_t)((b*8 + wv)*2048 + n0 + t*16 + l15))*64 + qd*8;
    qf[t][0] = *(const half8*)qp;
    qf[t][1] = *(const half8*)(qp + 32);
  }

  auto issueK = [&](int it) {
#pragma unroll
    for (int j = 0; j < 2; j++) {
      const int bk = j*64 + lane;
      const int m = bk >> 3, c = bk & 7;
      const int cp = c ^ (m & 7);
      GLOAD16(kbase + (size_t)(it*16 + m)*64 + cp*8, &KB[wv][j*512]);
    }
  };
  auto issueV = [&](int it) {
#pragma unroll
    for (int j = 0; j < 2; j++) {
      const int bk = j*64 + lane;
      const int d = bk >> 1, c = bk & 1;
      const int cp = c ^ ((d >> 2) & 1);
      GLOAD16(vbase + (size_t)d*2048 + it*16 + cp*8, &VB[wv][j*512]);
    }
  };
  auto qk_to_sb = [&](int buf) {
    half8 ka0 = *(const half8*)&KB[wv][l15*64 + ((qd       ^ (l15 & 7))*8)];
    half8 ka1 = *(const half8*)&KB[wv][l15*64 + (((4 + qd) ^ (l15 & 7))*8)];
#pragma unroll
    for (int t = 0; t < 2; t++) {
      f32x4 a = {0.f,0.f,0.f,0.f};
      a = MFMA32(ka0, qf[t][0], a);
      a = MFMA32(ka1, qf[t][1], a);
#pragma unroll
      for (int i = 0; i < 4; i++)
        Sb[buf][t][(l15 >> 1)*324 + (qd*4 + i)*20 + wv + 8*(l15 & 1)] = (_Float16)a[i];
    }
  };

  f32x4 og[2][4];
#pragma unroll
  for (int t = 0; t < 2; t++)
#pragma unroll
    for (int dt = 0; dt < 4; dt++)
      og[t][dt] = (f32x4){0.f,0.f,0.f,0.f};

  issueK(0);
  __syncthreads();

  for (int it = 0; it <= 65; it++) {
    if (it < 64) {
      qk_to_sb(it & 1);
      if (it + 1 < 64) issueK(it + 1);
    }
    if (it >= 1 && it <= 64) {
      const int buf = (it - 1) & 1;
#pragma unroll
      for (int t = 0; t < 2; t++) {
        half4 b1 = *(const half4*)&Sb[buf][t][wv*324 + l15*20 + qd*4];
        f32x4 c1 = MFMA16(a1f, b1, cs[t]);
        half4 a2;
#pragma unroll
        for (int i = 0; i < 4; i++) a2[i] = (_Float16)EXP2F(c1[i]);
        f32x4 c2 = MFMA16(a2, b2f, ((f32x4){0.f,0.f,0.f,0.f}));
        half4 w4;
#pragma unroll
        for (int i = 0; i < 4; i++) w4[i] = (_Float16)c2[i];
        *(half4*)&Wb[buf][t][(l15 & 7)*324 + (wv*2 + (l15 >> 3))*20 + qd*4] = w4;
      }
    }
    if (it >= 2) {
      const int buf = (it - 2) & 1;
      half4 vb[4];
#pragma unroll
      for (int dt = 0; dt < 4; dt++) {
        const int rv = dt*16 + l15;
        vb[dt] = *(const half4*)&VB[wv][rv*16 +
                  (((qd >> 1) ^ ((rv >> 2) & 1))*8) + (qd & 1)*4];
      }
#pragma unroll
      for (int t = 0; t < 2; t++) {
        half4 af = *(const half4*)&Wb[buf][t][wv*324 + l15*20 + qd*4];
#pragma unroll
        for (int dt = 0; dt < 4; dt++)
          og[t][dt] = MFMA16(af, vb[dt], og[t][dt]);
      }
    }
    if (it >= 1 && it <= 64) issueV(it - 1);   // after VB reads (in-wave WAR safe)
    __syncthreads();
  }

  // epilogue: og[t][dt][i] -> (n = n0+t*16+qd*4+i, col = wv*64 + dt*16 + l15)
  _Float16* Op = Obuf + (size_t)mh * OPART + ((size_t)(b*2048 + n0))*512;
#pragma unroll
  for (int t = 0; t < 2; t++)
#pragma unroll
    for (int dt = 0; dt < 4; dt++)
#pragma unroll
      for (int i = 0; i < 4; i++)
        Op[(size_t)(t*16 + qd*4 + i)*512 + wv*64 + dt*16 + l15] = (_Float16)og[t][dt][i];
}

// ---------------------------------------------------------------------------
// K4: output projection summing 2 partial O buffers.
// out[8192,512] = (O0+O1) @ w_out[512,512] + b_out (fp32 out)
// ---------------------------------------------------------------------------
__global__ __launch_bounds__(256)
void k_oproj(const _Float16* __restrict__ Ob, const float* __restrict__ w,
             const float* __restrict__ bias, float* __restrict__ out)
{
  __shared__ __align__(16) _Float16 Xs[64*40];
  __shared__ __align__(16) _Float16 Wt[64*40];
  const int tid = threadIdx.x;
  const int wv = tid >> 6, lane = tid & 63, l15 = lane & 15, qd = lane >> 4;
  const int row0 = blockIdx.x * 64, col0 = blockIdx.y * 64;
  const int xr = tid >> 2, xc = (tid & 3) * 8;
  const int wk = tid >> 3, wc = (tid & 7) * 8;

  f32x4 acc[4] = {{0.f,0.f,0.f,0.f},{0.f,0.f,0.f,0.f},{0.f,0.f,0.f,0.f},{0.f,0.f,0.f,0.f}};

  for (int k0 = 0; k0 < 512; k0 += 32) {
    const size_t idx = (size_t)(row0 + xr)*512 + k0 + xc;
    half8 a0 = *(const half8*)(Ob + idx);
    half8 a1 = *(const half8*)(Ob + OPART + idx);
    *(half8*)&Xs[xr*40 + xc] = a0 + a1;
    f32x4 b0 = *(const f32x4*)(w + (size_t)(k0 + wk)*512 + col0 + wc);
    f32x4 b1 = *(const f32x4*)(w + (size_t)(k0 + wk)*512 + col0 + wc + 4);
#pragma unroll
    for (int j = 0; j < 4; j++) {
      Wt[(wc+j  )*40 + wk] = (_Float16)b0[j];
      Wt[(wc+j+4)*40 + wk] = (_Float16)b1[j];
    }
    __syncthreads();
    half8 af = *(const half8*)&Xs[(wv*16 + l15)*40 + qd*8];
#pragma unroll
    for (int ct = 0; ct < 4; ct++) {
      half8 bf = *(const half8*)&Wt[(ct*16 + l15)*40 + qd*8];
      acc[ct] = MFMA32(af, bf, acc[ct]);
    }
    __syncthreads();
  }
#pragma unroll
  for (int ct = 0; ct < 4; ct++) {
    const int c = col0 + ct*16 + l15;
    const float bv = bias[c];
#pragma unroll
    for (int i = 0; i < 4; i++) {
      const int row = row0 + wv*16 + qd*4 + i;
      out[(size_t)row*512 + c] = acc[ct][i] + bv;
    }
  }
}

// ---------------------------------------------------------------------------
extern "C" void kernel_launch(void* const* d_in, const int* in_sizes, int n_in,
                              void* d_out, int out_size, void* d_ws, size_t ws_size,
                              hipStream_t stream)
{
  (void)in_sizes; (void)n_in; (void)out_size;
  const float* x     = (const float*)d_in[0];
  const float* w_qkv = (const float*)d_in[1];
  const float* b_qkv = (const float*)d_in[2];
  const float* th1   = (const float*)d_in[3];
  const float* th2   = (const float*)d_in[4];
  const float* w_out = (const float*)d_in[5];
  const float* b_out = (const float*)d_in[6];
  float* out = (float*)d_out;

  char* ws = (char*)d_ws;
  _Float16* Qh   = (_Float16*)(ws + QH_OFF);
  _Float16* Kh   = (_Float16*)(ws + KH_OFF);
  _Float16* Vt   = (_Float16*)(ws + VT_OFF);
  float*    Lsum = (float*)   (ws + LS_OFF);
  _Float16* Obuf = (_Float16*)(ws + O_OFF);
  if (ws_size < ((size_t)41 << 20)) return;  // need 41 MB scratch

  k_qkv  <<<dim3(128, 24), 256, 0, stream>>>(x, w_qkv, b_qkv, Qh, Kh, Vt);
  k_pass1<<<dim3(512),     512, 0, stream>>>(Qh, Kh, th1, Lsum);
  k_pass2<<<dim3(512),     512, 0, stream>>>(Qh, Kh, Vt, Lsum, th1, th2, Obuf);
  k_oproj<<<dim3(128, 8),  256, 0, stream>>>(Obuf, w_out, b_out, out);
}

// Round 13
// 324.884 us; speedup vs baseline: 1.6552x; 1.0830x over previous
//
#include <hip/hip_runtime.h>

typedef _Float16 half8  __attribute__((ext_vector_type(8)));
typedef _Float16 half4  __attribute__((ext_vector_type(4)));
typedef float    f32x4  __attribute__((ext_vector_type(4)));

#define MFMA32(a,b,c) __builtin_amdgcn_mfma_f32_16x16x32_f16(a,b,c,0,0,0)
#define MFMA16(a,b,c) __builtin_amdgcn_mfma_f32_16x16x16f16(a,b,c,0,0,0)

#if __has_builtin(__builtin_amdgcn_exp2f)
#define EXP2F(x) __builtin_amdgcn_exp2f(x)
#else
#define EXP2F(x) exp2f(x)
#endif

// Async global->LDS, 16B/lane, dest = wave-uniform base + lane*16.
// Side-effecting: compiler cannot sink it. __syncthreads() drains vmcnt(0).
#define GLOAD16(gp, lp) __builtin_amdgcn_global_load_lds(                      \
    (const __attribute__((address_space(1))) void*)(gp),                       \
    (__attribute__((address_space(3))) void*)(lp), 16, 0, 0)

// scale = DH^-0.5 = 1/8, folded together with log2(e) into Q so softmax uses exp2.
static constexpr float SCALE_LOG2E = 0.18033688011112042f;

static constexpr size_t QH_OFF = 0;
static constexpr size_t KH_OFF = (size_t)8  << 20;
static constexpr size_t VT_OFF = (size_t)16 << 20;
static constexpr size_t LS_OFF = (size_t)24 << 20;
static constexpr size_t O_OFF  = (size_t)25 << 20;
static constexpr size_t LPART  = (size_t)4*8*2048;   // floats per m-half L partial
static constexpr size_t OPART  = (size_t)8192*512;   // halves per O partial
// Xf / Wt f16 staging buffers alias the Obuf region (consumed by k_qkv before
// k_pass2 overwrites it with O partials — stream-ordered, no extra WS).

// G-stride for Sb/Wb: 340 halves = 170 words; l15*10 mod 32 all-distinct.
static constexpr int GS = 340;

// ---------------------------------------------------------------------------
// K0a: X fp32 -> f16.  grid 4096 x 256 threads, 4 elems/thread.
// ---------------------------------------------------------------------------
__global__ __launch_bounds__(256)
void k_cvtx(const float* __restrict__ x, _Float16* __restrict__ xf)
{
  const size_t i = ((size_t)blockIdx.x*256 + threadIdx.x)*4;
  f32x4 v = *(const f32x4*)(x + i);
  half4 h;
#pragma unroll
  for (int j = 0; j < 4; j++) h[j] = (_Float16)v[j];
  *(half4*)(xf + i) = h;
}

// ---------------------------------------------------------------------------
// K0b: W fp32 [512k][1536c] -> f16 transposed Wt [1536c][512k]. LDS-tiled.
// grid (16 k-tiles, 48 c-tiles) x 256 threads.
// ---------------------------------------------------------------------------
__global__ __launch_bounds__(256)
void k_cvtw(const float* __restrict__ w, _Float16* __restrict__ wt)
{
  __shared__ _Float16 T[32][36];
  const int kt = blockIdx.x, ct = blockIdx.y;
  const int r = threadIdx.x >> 3, c4 = (threadIdx.x & 7)*4;
  f32x4 v = *(const f32x4*)(w + (size_t)(kt*32 + r)*1536 + ct*32 + c4);
#pragma unroll
  for (int j = 0; j < 4; j++) T[r][c4 + j] = (_Float16)v[j];
  __syncthreads();
  half4 o;
#pragma unroll
  for (int j = 0; j < 4; j++) o[j] = T[c4 + j][r];
  *(half4*)(wt + (size_t)(ct*32 + r)*512 + kt*32 + c4) = o;
}

// ---------------------------------------------------------------------------
// K1: qkv projection, async-staged all-f16. C[8192,1536] = Xf @ Wt^T + b.
// Per k-step: wave wv stages its 16 X-rows + 16 Wt-rows via GLOAD16 with
// slot swizzle slot(r,o) = r*4 + (o ^ ((r>>1)&3)) (reads ~2-way = free).
// Scatters to Qh (xSCALE_LOG2E), Kh, Vt as before.
// ---------------------------------------------------------------------------
__global__ __launch_bounds__(256)
void k_qkv(const _Float16* __restrict__ xf, const _Float16* __restrict__ wt,
           const float* __restrict__ bias, _Float16* __restrict__ Qh,
           _Float16* __restrict__ Kh, _Float16* __restrict__ Vt)
{
  __shared__ __align__(16) _Float16 Xs[2048];   // 64 rows x 32 k
  __shared__ __align__(16) _Float16 Ws[2048];   // 64 cols x 32 k
  const int tid = threadIdx.x;
  const int wv = tid >> 6, lane = tid & 63, l15 = lane & 15, qd = lane >> 4;
  const int row0 = blockIdx.x * 64, col0 = blockIdx.y * 64;

  // staging address for this lane (slot = wv*64 + lane)
  const int sslot = wv*64 + lane;
  const int sr = sslot >> 2, so = (sslot & 3) ^ ((sr >> 1) & 3);

  f32x4 acc[4] = {{0.f,0.f,0.f,0.f},{0.f,0.f,0.f,0.f},{0.f,0.f,0.f,0.f},{0.f,0.f,0.f,0.f}};

  for (int k0 = 0; k0 < 512; k0 += 32) {
    GLOAD16(xf + (size_t)(row0 + sr)*512 + k0 + so*8, &Xs[wv*512]);
    GLOAD16(wt + (size_t)(col0 + sr)*512 + k0 + so*8, &Ws[wv*512]);
    __syncthreads();
    const int ra = wv*16 + l15;
    half8 af = *(const half8*)&Xs[(ra*4 + (qd ^ ((ra >> 1) & 3)))*8];
#pragma unroll
    for (int ct = 0; ct < 4; ct++) {
      const int rb = ct*16 + l15;
      half8 bf = *(const half8*)&Ws[(rb*4 + (qd ^ ((rb >> 1) & 3)))*8];
      acc[ct] = MFMA32(af, bf, acc[ct]);
    }
    __syncthreads();
  }
#pragma unroll
  for (int ct = 0; ct < 4; ct++) {
    const int c = col0 + ct*16 + l15;
    const int sec = c >> 9, hh = (c >> 6) & 7, d = c & 63;
    const float bv = bias[c];
#pragma unroll
    for (int i = 0; i < 4; i++) {
      const int row = row0 + wv*16 + qd*4 + i;
      const int bb = row >> 11, n = row & 2047;
      float v = acc[ct][i] + bv;
      if (sec == 0)
        Qh[((size_t)((bb*8 + hh)*2048 + n))*64 + d] = (_Float16)(v * SCALE_LOG2E);
      else if (sec == 1)
        Kh[((size_t)((bb*8 + hh)*2048 + n))*64 + d] = (_Float16)v;
      else
        Vt[((size_t)((bb*8 + hh)*64 + d))*2048 + n] = (_Float16)v;
    }
  }
}

// ---------------------------------------------------------------------------
// K2: pass 1 — softmax denominators over an m-half. Grid 512 = 64nt x (4b x 2mh).
// Block = 512 threads (8 waves), 32 n-rows. Sb G-stride 340 (conflict fix).
// ---------------------------------------------------------------------------
__global__ __launch_bounds__(512, 4)
void k_pass1(const _Float16* __restrict__ Qh, const _Float16* __restrict__ Kh,
             const float* __restrict__ th1, float* __restrict__ Lsum)
{
  __shared__ __align__(16) _Float16 KB[8][1024];     // 16384 B
  __shared__ __align__(16) _Float16 Sb[2][2][2704];  // 21632 B
  const int tid = threadIdx.x;
  const int wv = tid >> 6, lane = tid & 63, l15 = lane & 15, qd = lane >> 4;
  const int s = blockIdx.x & 7, nt = blockIdx.x >> 3;
  const int b = s >> 1, mh = s & 1;
  const int n0 = nt << 5;
  const _Float16* kbase = Kh + ((size_t)((b*8 + wv)*2048 + mh*1024))*64;

  half4 a1f;
#pragma unroll
  for (int j = 0; j < 4; j++)
    a1f[j] = ((l15 >> 3) == (qd >> 1)) ? (_Float16)th1[(l15 & 7)*8 + (qd & 1)*4 + j]
                                       : (_Float16)0.f;

  half8 qf[2][2];
#pragma unroll
  for (int t = 0; t < 2; t++) {
    const _Float16* qp = Qh + ((size_t)((b*8 + wv)*2048 + n0 + t*16 + l15))*64 + qd*8;
    qf[t][0] = *(const half8*)qp;
    qf[t][1] = *(const half8*)(qp + 32);
  }

  auto issueK = [&](int it) {
#pragma unroll
    for (int j = 0; j < 2; j++) {
      const int bk = j*64 + lane;
      const int m = bk >> 3, c = bk & 7;
      const int cp = c ^ (m & 7);
      GLOAD16(kbase + (size_t)(it*16 + m)*64 + cp*8, &KB[wv][j*512]);
    }
  };
  auto qk_to_sb = [&](int buf) {
    half8 ka0 = *(const half8*)&KB[wv][l15*64 + ((qd       ^ (l15 & 7))*8)];
    half8 ka1 = *(const half8*)&KB[wv][l15*64 + (((4 + qd) ^ (l15 & 7))*8)];
#pragma unroll
    for (int t = 0; t < 2; t++) {
      f32x4 a = {0.f,0.f,0.f,0.f};
      a = MFMA32(ka0, qf[t][0], a);
      a = MFMA32(ka1, qf[t][1], a);
#pragma unroll
      for (int i = 0; i < 4; i++)
        Sb[buf][t][(l15 >> 1)*GS + (qd*4 + i)*20 + wv + 8*(l15 & 1)] = (_Float16)a[i];
    }
  };

  float lacc[2][4];
#pragma unroll
  for (int t = 0; t < 2; t++)
#pragma unroll
    for (int i = 0; i < 4; i++) lacc[t][i] = 0.f;

  issueK(0);
  __syncthreads();
  for (int it = 0; it <= 64; it++) {
    if (it < 64) {
      qk_to_sb(it & 1);
      if (it + 1 < 64) issueK(it + 1);
    }
    if (it >= 1) {
      const int buf = (it - 1) & 1;
#pragma unroll
      for (int t = 0; t < 2; t++) {
        half4 b1 = *(const half4*)&Sb[buf][t][wv*GS + l15*20 + qd*4];
        f32x4 c1 = MFMA16(a1f, b1, ((f32x4){0.f,0.f,0.f,0.f}));
#pragma unroll
        for (int i = 0; i < 4; i++) lacc[t][i] += EXP2F(c1[i]);
      }
    }
    __syncthreads();
  }

#pragma unroll
  for (int t = 0; t < 2; t++)
#pragma unroll
    for (int i = 0; i < 4; i++) {
      float v = lacc[t][i];
      v += __shfl_xor(v, 1); v += __shfl_xor(v, 2);
      v += __shfl_xor(v, 4); v += __shfl_xor(v, 8);
      lacc[t][i] = v;
    }
  if (l15 == 0) {
#pragma unroll
    for (int t = 0; t < 2; t++)
#pragma unroll
      for (int i = 0; i < 4; i++) {
        const int n = n0 + t*16 + wv*2 + (qd >> 1);
        const int g = (qd & 1)*4 + i;
        Lsum[(size_t)mh*LPART + (size_t)(b*8 + g)*2048 + n] = lacc[t][i];
      }
  }
}

// ---------------------------------------------------------------------------
// K3: pass 2 over an m-half. Sb/Wb G-stride 340; VB chunk-remap: slot =
// mhalf*64 + d -> read banks 4*(l15&7)+2*(qd&1), conflict-free at b64 floor.
// ---------------------------------------------------------------------------
__global__ __launch_bounds__(512, 4)
void k_pass2(const _Float16* __restrict__ Qh, const _Float16* __restrict__ Kh,
             const _Float16* __restrict__ Vt, const float* __restrict__ Lsum,
             const float* __restrict__ th1, const float* __restrict__ th2,
             _Float16* __restrict__ Obuf)
{
  __shared__ __align__(16) _Float16 KB[8][1024];     // 16384 B
  __shared__ __align__(16) _Float16 VB[8][1024];     // 16384 B [wv][slot=mh*64+d]
  __shared__ __align__(16) _Float16 Sb[2][2][2704];  // 21632 B
  __shared__ __align__(16) _Float16 Wb[2][2][2704];  // 21632 B  (total 76032 B)
  const int tid = threadIdx.x;
  const int wv = tid >> 6, lane = tid & 63, l15 = lane & 15, qd = lane >> 4;
  const int s = blockIdx.x & 7, nt = blockIdx.x >> 3;
  const int b = s >> 1, mh = s & 1;
  const int n0 = nt << 5;
  const _Float16* kbase = Kh + ((size_t)((b*8 + wv)*2048 + mh*1024))*64;
  const _Float16* vbase = Vt + (size_t)(b*8 + wv)*64*2048 + mh*1024;

  half4 a1f, b2f;
#pragma unroll
  for (int j = 0; j < 4; j++) {
    const bool diag = ((l15 >> 3) == (qd >> 1));
    a1f[j] = diag ? (_Float16)th1[(l15 & 7)*8 + (qd & 1)*4 + j] : (_Float16)0.f;
    b2f[j] = diag ? (_Float16)th2[(l15 & 7)*8 + (qd & 1)*4 + j] : (_Float16)0.f;
  }

  // softmax seed, hoisted to registers (constant per lane across all iters)
  f32x4 cs[2];
#pragma unroll
  for (int t = 0; t < 2; t++)
#pragma unroll
    for (int i = 0; i < 4; i++) {
      const int n = n0 + t*16 + wv*2 + (qd >> 1);
      const int g = (qd & 1)*4 + i;
      const size_t off = (size_t)(b*8 + g)*2048 + n;
      cs[t][i] = -__log2f(Lsum[off] + Lsum[off + LPART]);
    }

  half8 qf[2][2];
#pragma unroll
  for (int t = 0; t < 2; t++) {
    const _Float16* qp = Qh + ((size_t)((b*8 + wv)*2048 + n0 + t*16 + l15))*64 + qd*8;
    qf[t][0] = *(const half8*)qp;
    qf[t][1] = *(const half8*)(qp + 32);
  }

  auto issueK = [&](int it) {
#pragma unroll
    for (int j = 0; j < 2; j++) {
      const int bk = j*64 + lane;
      const int m = bk >> 3, c = bk & 7;
      const int cp = c ^ (m & 7);
      GLOAD16(kbase + (size_t)(it*16 + m)*64 + cp*8, &KB[wv][j*512]);
    }
  };
  // VB slots: issue j covers slots j*64+lane = (mhalf=j, d=lane)
  auto issueV = [&](int it) {
#pragma unroll
    for (int j = 0; j < 2; j++)
      GLOAD16(vbase + (size_t)lane*2048 + it*16 + j*8, &VB[wv][j*512]);
  };
  auto qk_to_sb = [&](int buf) {
    half8 ka0 = *(const half8*)&KB[wv][l15*64 + ((qd       ^ (l15 & 7))*8)];
    half8 ka1 = *(const half8*)&KB[wv][l15*64 + (((4 + qd) ^ (l15 & 7))*8)];
#pragma unroll
    for (int t = 0; t < 2; t++) {
      f32x4 a = {0.f,0.f,0.f,0.f};
      a = MFMA32(ka0, qf[t][0], a);
      a = MFMA32(ka1, qf[t][1], a);
#pragma unroll
      for (int i = 0; i < 4; i++)
        Sb[buf][t][(l15 >> 1)*GS + (qd*4 + i)*20 + wv + 8*(l15 & 1)] = (_Float16)a[i];
    }
  };

  f32x4 og[2][4];
#pragma unroll
  for (int t = 0; t < 2; t++)
#pragma unroll
    for (int dt = 0; dt < 4; dt++)
      og[t][dt] = (f32x4){0.f,0.f,0.f,0.f};

  issueK(0);
  __syncthreads();

  for (int it = 0; it <= 65; it++) {
    if (it < 64) {
      qk_to_sb(it & 1);
      if (it + 1 < 64) issueK(it + 1);
    }
    if (it >= 1 && it <= 64) {
      const int buf = (it - 1) & 1;
#pragma unroll
      for (int t = 0; t < 2; t++) {
        half4 b1 = *(const half4*)&Sb[buf][t][wv*GS + l15*20 + qd*4];
        f32x4 c1 = MFMA16(a1f, b1, cs[t]);
        half4 a2;
#pragma unroll
        for (int i = 0; i < 4; i++) a2[i] = (_Float16)EXP2F(c1[i]);
        f32x4 c2 = MFMA16(a2, b2f, ((f32x4){0.f,0.f,0.f,0.f}));
        half4 w4;
#pragma unroll
        for (int i = 0; i < 4; i++) w4[i] = (_Float16)c2[i];
        *(half4*)&Wb[buf][t][(l15 & 7)*GS + (wv*2 + (l15 >> 3))*20 + qd*4] = w4;
      }
    }
    if (it >= 2) {
      const int buf = (it - 2) & 1;
      half4 vb[4];
#pragma unroll
      for (int dt = 0; dt < 4; dt++)
        vb[dt] = *(const half4*)&VB[wv][((qd >> 1)*64 + dt*16 + l15)*8 + (qd & 1)*4];
#pragma unroll
      for (int t = 0; t < 2; t++) {
        half4 af = *(const half4*)&Wb[buf][t][wv*GS + l15*20 + qd*4];
#pragma unroll
        for (int dt = 0; dt < 4; dt++)
          og[t][dt] = MFMA16(af, vb[dt], og[t][dt]);
      }
    }
    if (it >= 1 && it <= 64) issueV(it - 1);   // after VB reads (in-wave WAR safe)
    __syncthreads();
  }

  // epilogue: og[t][dt][i] -> (n = n0+t*16+qd*4+i, col = wv*64 + dt*16 + l15)
  _Float16* Op = Obuf + (size_t)mh * OPART + ((size_t)(b*2048 + n0))*512;
#pragma unroll
  for (int t = 0; t < 2; t++)
#pragma unroll
    for (int dt = 0; dt < 4; dt++)
#pragma unroll
      for (int i = 0; i < 4; i++)
        Op[(size_t)(t*16 + qd*4 + i)*512 + wv*64 + dt*16 + l15] = (_Float16)og[t][dt][i];
}

// ---------------------------------------------------------------------------
// K4: output projection summing 2 partial O buffers.
// out[8192,512] = (O0+O1) @ w_out[512,512] + b_out (fp32 out)
// ---------------------------------------------------------------------------
__global__ __launch_bounds__(256)
void k_oproj(const _Float16* __restrict__ Ob, const float* __restrict__ w,
             const float* __restrict__ bias, float* __restrict__ out)
{
  __shared__ __align__(16) _Float16 Xs[64*40];
  __shared__ __align__(16) _Float16 Wt[64*40];
  const int tid = threadIdx.x;
  const int wv = tid >> 6, lane = tid & 63, l15 = lane & 15, qd = lane >> 4;
  const int row0 = blockIdx.x * 64, col0 = blockIdx.y * 64;
  const int xr = tid >> 2, xc = (tid & 3) * 8;
  const int wk = tid >> 3, wc = (tid & 7) * 8;

  f32x4 acc[4] = {{0.f,0.f,0.f,0.f},{0.f,0.f,0.f,0.f},{0.f,0.f,0.f,0.f},{0.f,0.f,0.f,0.f}};

  for (int k0 = 0; k0 < 512; k0 += 32) {
    const size_t idx = (size_t)(row0 + xr)*512 + k0 + xc;
    half8 a0 = *(const half8*)(Ob + idx);
    half8 a1 = *(const half8*)(Ob + OPART + idx);
    *(half8*)&Xs[xr*40 + xc] = a0 + a1;
    f32x4 b0 = *(const f32x4*)(w + (size_t)(k0 + wk)*512 + col0 + wc);
    f32x4 b1 = *(const f32x4*)(w + (size_t)(k0 + wk)*512 + col0 + wc + 4);
#pragma unroll
    for (int j = 0; j < 4; j++) {
      Wt[(wc+j  )*40 + wk] = (_Float16)b0[j];
      Wt[(wc+j+4)*40 + wk] = (_Float16)b1[j];
    }
    __syncthreads();
    half8 af = *(const half8*)&Xs[(wv*16 + l15)*40 + qd*8];
#pragma unroll
    for (int ct = 0; ct < 4; ct++) {
      half8 bf = *(const half8*)&Wt[(ct*16 + l15)*40 + qd*8];
      acc[ct] = MFMA32(af, bf, acc[ct]);
    }
    __syncthreads();
  }
#pragma unroll
  for (int ct = 0; ct < 4; ct++) {
    const int c = col0 + ct*16 + l15;
    const float bv = bias[c];
#pragma unroll
    for (int i = 0; i < 4; i++) {
      const int row = row0 + wv*16 + qd*4 + i;
      out[(size_t)row*512 + c] = acc[ct][i] + bv;
    }
  }
}

// ---------------------------------------------------------------------------
extern "C" void kernel_launch(void* const* d_in, const int* in_sizes, int n_in,
                              void* d_out, int out_size, void* d_ws, size_t ws_size,
                              hipStream_t stream)
{
  (void)in_sizes; (void)n_in; (void)out_size;
  const float* x     = (const float*)d_in[0];
  const float* w_qkv = (const float*)d_in[1];
  const float* b_qkv = (const float*)d_in[2];
  const float* th1   = (const float*)d_in[3];
  const float* th2   = (const float*)d_in[4];
  const float* w_out = (const float*)d_in[5];
  const float* b_out = (const float*)d_in[6];
  float* out = (float*)d_out;

  char* ws = (char*)d_ws;
  _Float16* Qh   = (_Float16*)(ws + QH_OFF);
  _Float16* Kh   = (_Float16*)(ws + KH_OFF);
  _Float16* Vt   = (_Float16*)(ws + VT_OFF);
  float*    Lsum = (float*)   (ws + LS_OFF);
  _Float16* Obuf = (_Float16*)(ws + O_OFF);
  // Xf/Wt alias the Obuf region (qkv consumes them before pass2 writes O)
  _Float16* Xf   = (_Float16*)(ws + O_OFF);
  _Float16* Wtf  = (_Float16*)(ws + O_OFF + ((size_t)8 << 20));
  if (ws_size < ((size_t)41 << 20)) return;  // need 41 MB scratch

  k_cvtx <<<dim3(4096),    256, 0, stream>>>(x, Xf);
  k_cvtw <<<dim3(16, 48),  256, 0, stream>>>(w_qkv, Wtf);
  k_qkv  <<<dim3(128, 24), 256, 0, stream>>>(Xf, Wtf, b_qkv, Qh, Kh, Vt);
  k_pass1<<<dim3(512),     512, 0, stream>>>(Qh, Kh, th1, Lsum);
  k_pass2<<<dim3(512),     512, 0, stream>>>(Qh, Kh, Vt, Lsum, th1, th2, Obuf);
  k_oproj<<<dim3(128, 8),  256, 0, stream>>>(Obuf, w_out, b_out, out);
}